// Round 2
// baseline (503.661 us; speedup 1.0000x reference)
//
#include <hip/hip_runtime.h>

#define NN 100000
#define NE 1600000
#define NF 256
#define HD 64
#define NC 32

#define BKS 8
#define NBK ((NN + 255) >> 8)      // 391 buckets of 256 nodes
#define CHUNK 4096                 // edges per bin_edges block
#define NBLK ((NE + CHUNK - 1) / CHUNK)  // 391

__device__ __forceinline__ float lrelu02(float x) { return fmaxf(x, 0.2f * x); }

// ---------------- CSR build via bucketed counting sort (unchanged) ----------------

__global__ __launch_bounds__(256) void bucket_hist(const int* __restrict__ dst, int* __restrict__ gcnt) {
    __shared__ int hist[NBK];
    int tid = threadIdx.x;
    for (int i = tid; i < NBK; i += 256) hist[i] = 0;
    __syncthreads();
    int base = blockIdx.x * CHUNK;
    #pragma unroll
    for (int k = 0; k < CHUNK / 256; k++) {
        int i = base + k * 256 + tid;
        if (i < NE) atomicAdd(&hist[dst[i] >> BKS], 1);
    }
    __syncthreads();
    for (int i = tid; i < NBK; i += 256) if (hist[i]) atomicAdd(&gcnt[i], hist[i]);
}

__global__ void bucket_scan(const int* __restrict__ gcnt, int* __restrict__ gbase, int* __restrict__ gcur) {
    __shared__ int sh[512];
    int tid = threadIdx.x;
    int v = (tid < NBK) ? gcnt[tid] : 0;
    sh[tid] = v;
    __syncthreads();
    for (int d = 1; d < 512; d <<= 1) {
        int t = (tid >= d) ? sh[tid - d] : 0;
        __syncthreads();
        sh[tid] += t;
        __syncthreads();
    }
    if (tid < NBK) { int ex = sh[tid] - v; gbase[tid] = ex; gcur[tid] = ex; }
}

__global__ __launch_bounds__(256) void bin_edges(const int* __restrict__ src, const int* __restrict__ dst,
                                                 int* __restrict__ gcur, int2* __restrict__ ebuf) {
    __shared__ int hist[NBK];
    __shared__ int excl[NBK];
    __shared__ int runbase[NBK];
    __shared__ int ssum[256];
    __shared__ int2 sorted[CHUNK];   // 32 KB
    int tid = threadIdx.x;
    int base = blockIdx.x * CHUNK;
    int n = NE - base; if (n > CHUNK) n = CHUNK;

    for (int i = tid; i < NBK; i += 256) hist[i] = 0;
    __syncthreads();

    int2 ed[CHUNK / 256];
    int bk[CHUNK / 256];
    #pragma unroll
    for (int k = 0; k < CHUNK / 256; k++) {
        int i = base + k * 256 + tid;
        if (i < NE) {
            ed[k] = make_int2(src[i], dst[i]);
            bk[k] = ed[k].y >> BKS;
            atomicAdd(&hist[bk[k]], 1);
        } else bk[k] = -1;
    }
    __syncthreads();
    int h0 = (2 * tid < NBK) ? hist[2 * tid] : 0;
    int h1 = (2 * tid + 1 < NBK) ? hist[2 * tid + 1] : 0;
    ssum[tid] = h0 + h1;
    __syncthreads();
    for (int d = 1; d < 256; d <<= 1) {
        int t = (tid >= d) ? ssum[tid - d] : 0;
        __syncthreads();
        ssum[tid] += t;
        __syncthreads();
    }
    int pref = ssum[tid] - (h0 + h1);
    if (2 * tid < NBK) excl[2 * tid] = pref;
    if (2 * tid + 1 < NBK) excl[2 * tid + 1] = pref + h0;
    for (int b = tid; b < NBK; b += 256) {
        int c = hist[b];
        runbase[b] = c ? atomicAdd(&gcur[b], c) : 0;
    }
    __syncthreads();
    #pragma unroll
    for (int k = 0; k < CHUNK / 256; k++) {
        if (bk[k] >= 0) {
            int r = atomicAdd(&excl[bk[k]], 1);
            sorted[r] = ed[k];
        }
    }
    __syncthreads();
    for (int i = tid; i < n; i += 256) {
        int2 e = sorted[i];
        int b = e.y >> BKS;
        int local_rank = i - (excl[b] - hist[b]);
        ebuf[runbase[b] + local_rank] = e;
    }
}

__global__ __launch_bounds__(256) void bucket_csr(const int2* __restrict__ ebuf, const int* __restrict__ gbase,
                                                  const int* __restrict__ gcnt,
                                                  int* __restrict__ offs, int* __restrict__ csr) {
    __shared__ int hist[256], cur[256], ssum[256];
    int b = blockIdx.x, tid = threadIdx.x;
    int ebeg = gbase[b], cnt = gcnt[b];
    int node0 = b << BKS;
    hist[tid] = 0;
    __syncthreads();
    for (int i = ebeg + tid; i < ebeg + cnt; i += 256)
        atomicAdd(&hist[ebuf[i].y & 255], 1);
    __syncthreads();
    int v = hist[tid];
    ssum[tid] = v;
    __syncthreads();
    for (int d = 1; d < 256; d <<= 1) {
        int t = (tid >= d) ? ssum[tid - d] : 0;
        __syncthreads();
        ssum[tid] += t;
        __syncthreads();
    }
    int ex = ebeg + ssum[tid] - v;
    cur[tid] = ex;
    int nnode = NN - node0; if (nnode > 256) nnode = 256;
    if (tid < nnode) offs[node0 + tid] = ex;
    if (b == NBK - 1 && tid == nnode - 1) offs[NN] = ebeg + cnt;
    __syncthreads();
    for (int i = ebeg + tid; i < ebeg + cnt; i += 256) {
        int2 e = ebuf[i];
        int pos = atomicAdd(&cur[e.y & 255], 1);
        csr[pos] = e.x;
    }
}

// ---------------- wave-per-colgroup GEMM: W via scalar loads (SGPR), x via LDS b64 ----------------
// 256 threads = 4 waves. Wave w owns cols [w*CPW, w*CPW+CPW). Lane owns 2 nodes.
// Per k: 1 ds_read_b64 (2 node x-vals) + CPW/4 s_load_dwordx4 of W (wave-uniform,
// scalar cache, zero LDS traffic) -> 2*CPW FMAs. LDS traffic drops ~6x vs prior
// layout -> LDS read BW off the critical path; VALU becomes the limiter.

template <int CIN, int COUT>
__global__ __launch_bounds__(256) void rb_gemm2(const float* __restrict__ in, const float* __restrict__ W,
                                                const float* __restrict__ a_s, const float* __restrict__ a_d,
                                                float* __restrict__ h, float* __restrict__ asv,
                                                float* __restrict__ adv) {
    const int KC  = 32;
    const int BN  = 128;
    const int BNP = BN + 4;
    const int CPW = COUT / 4;   // cols per wave: 16 (COUT=64) or 8 (COUT=32)
    const int JW  = CPW / 4;    // float4 groups per wave: 4 or 2
    __shared__ float xsT[KC * BNP];   // ~16.5 KB
    __shared__ float rs[4][BN];       // per-wave partial a_s dots
    __shared__ float rd[4][BN];       // per-wave partial a_d dots

    int tid  = threadIdx.x;
    int lane = tid & 63;
    int wave = tid >> 6;
    // readfirstlane -> provably wave-uniform -> W reads become s_load into SGPRs
    int c0 = __builtin_amdgcn_readfirstlane(wave) * CPW;
    int n0base = blockIdx.x * BN;

    float4 acc[2][JW];
    #pragma unroll
    for (int i = 0; i < 2; i++)
        #pragma unroll
        for (int j = 0; j < JW; j++) acc[i][j] = make_float4(0.f, 0.f, 0.f, 0.f);

    for (int k0 = 0; k0 < CIN; k0 += KC) {
        __syncthreads();
        // stage x transposed: coalesced float4 global reads, scatter into xsT[k][n]
        #pragma unroll
        for (int f = tid; f < BN * KC / 4; f += 256) {
            int n = f >> 3;
            int q = f & 7;
            int gn = n0base + n;
            float4 v = make_float4(0.f, 0.f, 0.f, 0.f);
            if (gn < NN) v = *(const float4*)&in[(size_t)gn * CIN + k0 + q * 4];
            xsT[(q * 4 + 0) * BNP + n] = v.x;
            xsT[(q * 4 + 1) * BNP + n] = v.y;
            xsT[(q * 4 + 2) * BNP + n] = v.z;
            xsT[(q * 4 + 3) * BNP + n] = v.w;
        }
        __syncthreads();
        const float* Wk = &W[(size_t)k0 * COUT + c0];
        #pragma unroll
        for (int k = 0; k < KC; k++) {
            float2 xv = *(const float2*)&xsT[k * BNP + (lane << 1)];   // 2 nodes, conflict-free b64
            #pragma unroll
            for (int j = 0; j < JW; j++) {
                float4 wv = *(const float4*)&Wk[k * COUT + j * 4];     // wave-uniform -> SGPR
                acc[0][j].x += xv.x * wv.x; acc[0][j].y += xv.x * wv.y;
                acc[0][j].z += xv.x * wv.z; acc[0][j].w += xv.x * wv.w;
                acc[1][j].x += xv.y * wv.x; acc[1][j].y += xv.y * wv.y;
                acc[1][j].z += xv.y * wv.z; acc[1][j].w += xv.y * wv.w;
            }
        }
    }

    // epilogue: h store + per-wave partial a_s/a_d dot (cols are wave-local -> lane-local)
    float vs0 = 0.f, vs1 = 0.f, vd0 = 0.f, vd1 = 0.f;
    #pragma unroll
    for (int j = 0; j < JW; j++) {
        float4 As = *(const float4*)&a_s[c0 + j * 4];
        float4 Ad = *(const float4*)&a_d[c0 + j * 4];
        vs0 += acc[0][j].x * As.x + acc[0][j].y * As.y + acc[0][j].z * As.z + acc[0][j].w * As.w;
        vs1 += acc[1][j].x * As.x + acc[1][j].y * As.y + acc[1][j].z * As.z + acc[1][j].w * As.w;
        vd0 += acc[0][j].x * Ad.x + acc[0][j].y * Ad.y + acc[0][j].z * Ad.z + acc[0][j].w * Ad.w;
        vd1 += acc[1][j].x * Ad.x + acc[1][j].y * Ad.y + acc[1][j].z * Ad.z + acc[1][j].w * Ad.w;
    }
    int n0 = n0base + (lane << 1);
    if (n0 < NN) {
        #pragma unroll
        for (int j = 0; j < JW; j++) *(float4*)&h[(size_t)n0 * COUT + c0 + j * 4] = acc[0][j];
    }
    if (n0 + 1 < NN) {
        #pragma unroll
        for (int j = 0; j < JW; j++) *(float4*)&h[(size_t)(n0 + 1) * COUT + c0 + j * 4] = acc[1][j];
    }
    rs[wave][(lane << 1) + 0] = vs0;
    rs[wave][(lane << 1) + 1] = vs1;
    rd[wave][(lane << 1) + 0] = vd0;
    rd[wave][(lane << 1) + 1] = vd1;
    __syncthreads();
    if (tid < BN) {
        int n = n0base + tid;
        if (n < NN) {
            asv[n] = rs[0][tid] + rs[1][tid] + rs[2][tid] + rs[3][tid];
            adv[n] = rd[0][tid] + rd[1][tid] + rd[2][tid] + rd[3][tid];
        }
    }
}

// ---------------- fused aggregate (unchanged) ----------------

template <int C, bool ACT>
__global__ __launch_bounds__(256) void gat_agg(const float* __restrict__ h, const float* __restrict__ asv,
                                               const float* __restrict__ adv, const int* __restrict__ offs,
                                               const int* __restrict__ csr,
                                               const float* __restrict__ bias, float* __restrict__ out) {
    const int LPR = C / 4;
    const int G = 64 / LPR;
    const float4* h4 = (const float4*)h;
    int lane = threadIdx.x & 63;
    int v = blockIdx.x * 4 + (threadIdx.x >> 6);
    int beg = offs[v], end = offs[v + 1];
    int g = lane / LPR, r = lane % LPR;
    float adv_v = adv[v];

    float4 acc = {0.f, 0.f, 0.f, 0.f};
    float dsum = 0.f;
    #pragma unroll 4
    for (int e = beg + g; e < end; e += G) {
        int s = csr[e];
        float ww = __expf(lrelu02(asv[s] + adv_v));
        float4 hv = h4[(size_t)s * LPR + r];
        dsum += ww;
        acc.x += ww * hv.x; acc.y += ww * hv.y; acc.z += ww * hv.z; acc.w += ww * hv.w;
    }
    #pragma unroll
    for (int off = LPR; off < 64; off <<= 1) {
        acc.x += __shfl_xor(acc.x, off);
        acc.y += __shfl_xor(acc.y, off);
        acc.z += __shfl_xor(acc.z, off);
        acc.w += __shfl_xor(acc.w, off);
        dsum += __shfl_xor(dsum, off);
    }
    if (g == 0) {
        float selfw = __expf(lrelu02(asv[v] + adv_v));
        float4 hs = h4[(size_t)v * LPR + r];
        acc.x += selfw * hs.x; acc.y += selfw * hs.y;
        acc.z += selfw * hs.z; acc.w += selfw * hs.w;
        dsum += selfw;
        float inv = 1.f / (dsum + 1e-16f);
        float4 bb = ((const float4*)bias)[r];
        float4 o;
        o.x = acc.x * inv + bb.x; o.y = acc.y * inv + bb.y;
        o.z = acc.z * inv + bb.z; o.w = acc.w * inv + bb.w;
        if (ACT) {
            o.x = fmaxf(o.x, 0.01f * o.x); o.y = fmaxf(o.y, 0.01f * o.y);
            o.z = fmaxf(o.z, 0.01f * o.z); o.w = fmaxf(o.w, 0.01f * o.w);
        }
        ((float4*)out)[(size_t)v * LPR + r] = o;
    }
}

// ---------------- launch ----------------

extern "C" void kernel_launch(void* const* d_in, const int* in_sizes, int n_in,
                              void* d_out, int out_size, void* d_ws, size_t ws_size,
                              hipStream_t stream) {
    const float* x   = (const float*)d_in[0];
    const int*   ei  = (const int*)d_in[1];
    const float* W1  = (const float*)d_in[2];
    const float* as1 = (const float*)d_in[3];
    const float* ad1 = (const float*)d_in[4];
    const float* b1  = (const float*)d_in[5];
    const float* W2  = (const float*)d_in[6];
    const float* as2 = (const float*)d_in[7];
    const float* ad2 = (const float*)d_in[8];
    const float* b2  = (const float*)d_in[9];
    const float* W3  = (const float*)d_in[10];
    const float* as3 = (const float*)d_in[11];
    const float* ad3 = (const float*)d_in[12];
    const float* b3  = (const float*)d_in[13];
    float* out = (float*)d_out;

    const int* srcp = ei;
    const int* dstp = ei + NE;

    char* w = (char*)d_ws;
    float* h     = (float*)w;   w += sizeof(float) * (size_t)NN * HD;
    float* featB = (float*)w;   w += sizeof(float) * (size_t)NN * HD;
    float* asv   = (float*)w;   w += sizeof(float) * NN;
    float* advv  = (float*)w;   w += sizeof(float) * NN;
    int* offs    = (int*)w;     w += sizeof(int) * (NN + 1);
    int* csr     = (int*)w;     w += sizeof(int) * (size_t)NE;
    int2* ebuf   = (int2*)w;    w += sizeof(int2) * (size_t)NE;
    int* gcnt    = (int*)w;     w += sizeof(int) * NBK;
    int* gbase   = (int*)w;     w += sizeof(int) * NBK;
    int* gcur    = (int*)w;     w += sizeof(int) * NBK;

    const int GB = (NN + 127) / 128;   // BN=128 -> 782 blocks

    // CSR build (bucketed counting sort; shared across all 3 layers)
    hipMemsetAsync(gcnt, 0, sizeof(int) * NBK, stream);
    bucket_hist<<<NBLK, 256, 0, stream>>>(dstp, gcnt);
    bucket_scan<<<1, 512, 0, stream>>>(gcnt, gbase, gcur);
    bin_edges<<<NBLK, 256, 0, stream>>>(srcp, dstp, gcur, ebuf);
    bucket_csr<<<NBK, 256, 0, stream>>>(ebuf, gbase, gcnt, offs, csr);

    // layer 1
    rb_gemm2<NF, HD><<<GB, 256, 0, stream>>>(x, W1, as1, ad1, h, asv, advv);
    gat_agg<HD, true><<<NN / 4, 256, 0, stream>>>(h, asv, advv, offs, csr, b1, featB);

    // layer 2
    rb_gemm2<HD, HD><<<GB, 256, 0, stream>>>(featB, W2, as2, ad2, h, asv, advv);
    gat_agg<HD, true><<<NN / 4, 256, 0, stream>>>(h, asv, advv, offs, csr, b2, featB);

    // layer 3
    rb_gemm2<HD, NC><<<GB, 256, 0, stream>>>(featB, W3, as3, ad3, h, asv, advv);
    gat_agg<NC, false><<<NN / 4, 256, 0, stream>>>(h, asv, advv, offs, csr, b3, out);
}

// Round 3
// 500.361 us; speedup vs baseline: 1.0066x; 1.0066x over previous
//
#include <hip/hip_runtime.h>

#define NN 100000
#define NE 1600000
#define NF 256
#define HD 64
#define NC 32

#define BKS 8
#define NBK ((NN + 255) >> 8)      // 391 buckets of 256 nodes
#define CHUNK 4096                 // edges per bin_edges block
#define NBLK ((NE + CHUNK - 1) / CHUNK)  // 391

__device__ __forceinline__ float lrelu02(float x) { return fmaxf(x, 0.2f * x); }

// ---------------- CSR build via bucketed counting sort (unchanged) ----------------

__global__ __launch_bounds__(256) void bucket_hist(const int* __restrict__ dst, int* __restrict__ gcnt) {
    __shared__ int hist[NBK];
    int tid = threadIdx.x;
    for (int i = tid; i < NBK; i += 256) hist[i] = 0;
    __syncthreads();
    int base = blockIdx.x * CHUNK;
    #pragma unroll
    for (int k = 0; k < CHUNK / 256; k++) {
        int i = base + k * 256 + tid;
        if (i < NE) atomicAdd(&hist[dst[i] >> BKS], 1);
    }
    __syncthreads();
    for (int i = tid; i < NBK; i += 256) if (hist[i]) atomicAdd(&gcnt[i], hist[i]);
}

__global__ void bucket_scan(const int* __restrict__ gcnt, int* __restrict__ gbase, int* __restrict__ gcur) {
    __shared__ int sh[512];
    int tid = threadIdx.x;
    int v = (tid < NBK) ? gcnt[tid] : 0;
    sh[tid] = v;
    __syncthreads();
    for (int d = 1; d < 512; d <<= 1) {
        int t = (tid >= d) ? sh[tid - d] : 0;
        __syncthreads();
        sh[tid] += t;
        __syncthreads();
    }
    if (tid < NBK) { int ex = sh[tid] - v; gbase[tid] = ex; gcur[tid] = ex; }
}

__global__ __launch_bounds__(256) void bin_edges(const int* __restrict__ src, const int* __restrict__ dst,
                                                 int* __restrict__ gcur, int2* __restrict__ ebuf) {
    __shared__ int hist[NBK];
    __shared__ int excl[NBK];
    __shared__ int runbase[NBK];
    __shared__ int ssum[256];
    __shared__ int2 sorted[CHUNK];   // 32 KB
    int tid = threadIdx.x;
    int base = blockIdx.x * CHUNK;
    int n = NE - base; if (n > CHUNK) n = CHUNK;

    for (int i = tid; i < NBK; i += 256) hist[i] = 0;
    __syncthreads();

    int2 ed[CHUNK / 256];
    int bk[CHUNK / 256];
    #pragma unroll
    for (int k = 0; k < CHUNK / 256; k++) {
        int i = base + k * 256 + tid;
        if (i < NE) {
            ed[k] = make_int2(src[i], dst[i]);
            bk[k] = ed[k].y >> BKS;
            atomicAdd(&hist[bk[k]], 1);
        } else bk[k] = -1;
    }
    __syncthreads();
    int h0 = (2 * tid < NBK) ? hist[2 * tid] : 0;
    int h1 = (2 * tid + 1 < NBK) ? hist[2 * tid + 1] : 0;
    ssum[tid] = h0 + h1;
    __syncthreads();
    for (int d = 1; d < 256; d <<= 1) {
        int t = (tid >= d) ? ssum[tid - d] : 0;
        __syncthreads();
        ssum[tid] += t;
        __syncthreads();
    }
    int pref = ssum[tid] - (h0 + h1);
    if (2 * tid < NBK) excl[2 * tid] = pref;
    if (2 * tid + 1 < NBK) excl[2 * tid + 1] = pref + h0;
    for (int b = tid; b < NBK; b += 256) {
        int c = hist[b];
        runbase[b] = c ? atomicAdd(&gcur[b], c) : 0;
    }
    __syncthreads();
    #pragma unroll
    for (int k = 0; k < CHUNK / 256; k++) {
        if (bk[k] >= 0) {
            int r = atomicAdd(&excl[bk[k]], 1);
            sorted[r] = ed[k];
        }
    }
    __syncthreads();
    for (int i = tid; i < n; i += 256) {
        int2 e = sorted[i];
        int b = e.y >> BKS;
        int local_rank = i - (excl[b] - hist[b]);
        ebuf[runbase[b] + local_rank] = e;
    }
}

__global__ __launch_bounds__(256) void bucket_csr(const int2* __restrict__ ebuf, const int* __restrict__ gbase,
                                                  const int* __restrict__ gcnt,
                                                  int* __restrict__ offs, int* __restrict__ csr) {
    __shared__ int hist[256], cur[256], ssum[256];
    int b = blockIdx.x, tid = threadIdx.x;
    int ebeg = gbase[b], cnt = gcnt[b];
    int node0 = b << BKS;
    hist[tid] = 0;
    __syncthreads();
    for (int i = ebeg + tid; i < ebeg + cnt; i += 256)
        atomicAdd(&hist[ebuf[i].y & 255], 1);
    __syncthreads();
    int v = hist[tid];
    ssum[tid] = v;
    __syncthreads();
    for (int d = 1; d < 256; d <<= 1) {
        int t = (tid >= d) ? ssum[tid - d] : 0;
        __syncthreads();
        ssum[tid] += t;
        __syncthreads();
    }
    int ex = ebeg + ssum[tid] - v;
    cur[tid] = ex;
    int nnode = NN - node0; if (nnode > 256) nnode = 256;
    if (tid < nnode) offs[node0 + tid] = ex;
    if (b == NBK - 1 && tid == nnode - 1) offs[NN] = ebeg + cnt;
    __syncthreads();
    for (int i = ebeg + tid; i < ebeg + cnt; i += 256) {
        int2 e = ebuf[i];
        int pos = atomicAdd(&cur[e.y & 255], 1);
        csr[pos] = e.x;
    }
}

// ---------------- register-blocked GEMM, 8n x 8c per thread ----------------
// R0 structure (x and W both in LDS, broadcast reads) but deeper register
// blocking: NPT nodes x CPT cols per thread. Per k: (NPT/4 + CPT/4) b128 LDS
// reads feed NPT*CPT FMAs -> 1.0 LDS-B/FMA (was 1.5). LDS is the shared
// resource (1 unit / 4 SIMDs), so this is a direct 1.5x cut on the ceiling.

template <int CIN, int COUT, int NPT, int CPT>
__global__ __launch_bounds__(256) void rb_gemm3(const float* __restrict__ in, const float* __restrict__ W,
                                                const float* __restrict__ a_s, const float* __restrict__ a_d,
                                                float* __restrict__ h, float* __restrict__ asv,
                                                float* __restrict__ adv) {
    const int KC  = 32;
    const int CG  = COUT / CPT;      // col groups (8 or 4)
    const int NG  = 256 / CG;        // node groups
    const int BN  = NG * NPT;        // nodes per block (256)
    const int BNP = BN + 4;
    const int NP4 = NPT / 4;
    const int CP4 = CPT / 4;
    __shared__ float xsT[KC * BNP];          // 33.3 KB (BN=256)
    __shared__ float Wl[KC * COUT];          // 8 KB (COUT=64)

    int tid = threadIdx.x;
    int cg  = tid % CG;
    int ng  = tid / CG;
    int c0  = cg * CPT;
    int n0  = ng * NPT;
    int n0base = blockIdx.x * BN;

    float4 acc[NPT][CP4];
    #pragma unroll
    for (int i = 0; i < NPT; i++)
        #pragma unroll
        for (int j = 0; j < CP4; j++) acc[i][j] = make_float4(0.f, 0.f, 0.f, 0.f);

    for (int k0 = 0; k0 < CIN; k0 += KC) {
        __syncthreads();
        // stage x transposed: coalesced float4 global read, scatter to xsT[k][n]
        #pragma unroll
        for (int f = tid; f < BN * KC / 4; f += 256) {
            int n = f >> 3;              // / (KC/4)
            int q = f & 7;
            int gn = n0base + n;
            float4 v = make_float4(0.f, 0.f, 0.f, 0.f);
            if (gn < NN) v = *(const float4*)&in[(size_t)gn * CIN + k0 + q * 4];
            xsT[(q * 4 + 0) * BNP + n] = v.x;
            xsT[(q * 4 + 1) * BNP + n] = v.y;
            xsT[(q * 4 + 2) * BNP + n] = v.z;
            xsT[(q * 4 + 3) * BNP + n] = v.w;
        }
        // stage W chunk (row-major, coalesced)
        #pragma unroll
        for (int f = tid; f < KC * COUT / 4; f += 256)
            *(float4*)&Wl[f * 4] = *(const float4*)&W[(size_t)k0 * COUT + f * 4];
        __syncthreads();
        #pragma unroll 2
        for (int k = 0; k < KC; k++) {
            float4 xv[NP4];
            #pragma unroll
            for (int p = 0; p < NP4; p++) xv[p] = *(const float4*)&xsT[k * BNP + n0 + p * 4];
            float4 wv[CP4];
            #pragma unroll
            for (int j = 0; j < CP4; j++) wv[j] = *(const float4*)&Wl[k * COUT + c0 + j * 4];
            #pragma unroll
            for (int i = 0; i < NPT; i++) {
                float xc = (i & 3) == 0 ? xv[i >> 2].x : (i & 3) == 1 ? xv[i >> 2].y
                         : (i & 3) == 2 ? xv[i >> 2].z : xv[i >> 2].w;
                #pragma unroll
                for (int j = 0; j < CP4; j++) {
                    acc[i][j].x += xc * wv[j].x; acc[i][j].y += xc * wv[j].y;
                    acc[i][j].z += xc * wv[j].z; acc[i][j].w += xc * wv[j].w;
                }
            }
        }
    }

    // epilogue: h store + a_s/a_d dots, shfl-reduce across the CG col-groups
    float4 As[CP4], Ad[CP4];
    #pragma unroll
    for (int j = 0; j < CP4; j++) {
        As[j] = *(const float4*)&a_s[c0 + j * 4];
        Ad[j] = *(const float4*)&a_d[c0 + j * 4];
    }
    #pragma unroll
    for (int i = 0; i < NPT; i++) {
        int gn = n0base + n0 + i;
        if (gn < NN) {
            #pragma unroll
            for (int j = 0; j < CP4; j++)
                *(float4*)&h[(size_t)gn * COUT + c0 + j * 4] = acc[i][j];
        }
        float vs = 0.f, vd = 0.f;
        #pragma unroll
        for (int j = 0; j < CP4; j++) {
            vs += acc[i][j].x * As[j].x + acc[i][j].y * As[j].y
                + acc[i][j].z * As[j].z + acc[i][j].w * As[j].w;
            vd += acc[i][j].x * Ad[j].x + acc[i][j].y * Ad[j].y
                + acc[i][j].z * Ad[j].z + acc[i][j].w * Ad[j].w;
        }
        #pragma unroll
        for (int off = 1; off < CG; off <<= 1) { vs += __shfl_xor(vs, off); vd += __shfl_xor(vd, off); }
        if (cg == 0 && gn < NN) { asv[gn] = vs; adv[gn] = vd; }
    }
}

// ---------------- fused aggregate (unchanged) ----------------

template <int C, bool ACT>
__global__ __launch_bounds__(256) void gat_agg(const float* __restrict__ h, const float* __restrict__ asv,
                                               const float* __restrict__ adv, const int* __restrict__ offs,
                                               const int* __restrict__ csr,
                                               const float* __restrict__ bias, float* __restrict__ out) {
    const int LPR = C / 4;
    const int G = 64 / LPR;
    const float4* h4 = (const float4*)h;
    int lane = threadIdx.x & 63;
    int v = blockIdx.x * 4 + (threadIdx.x >> 6);
    int beg = offs[v], end = offs[v + 1];
    int g = lane / LPR, r = lane % LPR;
    float adv_v = adv[v];

    float4 acc = {0.f, 0.f, 0.f, 0.f};
    float dsum = 0.f;
    #pragma unroll 4
    for (int e = beg + g; e < end; e += G) {
        int s = csr[e];
        float ww = __expf(lrelu02(asv[s] + adv_v));
        float4 hv = h4[(size_t)s * LPR + r];
        dsum += ww;
        acc.x += ww * hv.x; acc.y += ww * hv.y; acc.z += ww * hv.z; acc.w += ww * hv.w;
    }
    #pragma unroll
    for (int off = LPR; off < 64; off <<= 1) {
        acc.x += __shfl_xor(acc.x, off);
        acc.y += __shfl_xor(acc.y, off);
        acc.z += __shfl_xor(acc.z, off);
        acc.w += __shfl_xor(acc.w, off);
        dsum += __shfl_xor(dsum, off);
    }
    if (g == 0) {
        float selfw = __expf(lrelu02(asv[v] + adv_v));
        float4 hs = h4[(size_t)v * LPR + r];
        acc.x += selfw * hs.x; acc.y += selfw * hs.y;
        acc.z += selfw * hs.z; acc.w += selfw * hs.w;
        dsum += selfw;
        float inv = 1.f / (dsum + 1e-16f);
        float4 bb = ((const float4*)bias)[r];
        float4 o;
        o.x = acc.x * inv + bb.x; o.y = acc.y * inv + bb.y;
        o.z = acc.z * inv + bb.z; o.w = acc.w * inv + bb.w;
        if (ACT) {
            o.x = fmaxf(o.x, 0.01f * o.x); o.y = fmaxf(o.y, 0.01f * o.y);
            o.z = fmaxf(o.z, 0.01f * o.z); o.w = fmaxf(o.w, 0.01f * o.w);
        }
        ((float4*)out)[(size_t)v * LPR + r] = o;
    }
}

// ---------------- launch ----------------

extern "C" void kernel_launch(void* const* d_in, const int* in_sizes, int n_in,
                              void* d_out, int out_size, void* d_ws, size_t ws_size,
                              hipStream_t stream) {
    const float* x   = (const float*)d_in[0];
    const int*   ei  = (const int*)d_in[1];
    const float* W1  = (const float*)d_in[2];
    const float* as1 = (const float*)d_in[3];
    const float* ad1 = (const float*)d_in[4];
    const float* b1  = (const float*)d_in[5];
    const float* W2  = (const float*)d_in[6];
    const float* as2 = (const float*)d_in[7];
    const float* ad2 = (const float*)d_in[8];
    const float* b2  = (const float*)d_in[9];
    const float* W3  = (const float*)d_in[10];
    const float* as3 = (const float*)d_in[11];
    const float* ad3 = (const float*)d_in[12];
    const float* b3  = (const float*)d_in[13];
    float* out = (float*)d_out;

    const int* srcp = ei;
    const int* dstp = ei + NE;

    char* w = (char*)d_ws;
    float* h     = (float*)w;   w += sizeof(float) * (size_t)NN * HD;
    float* featB = (float*)w;   w += sizeof(float) * (size_t)NN * HD;
    float* asv   = (float*)w;   w += sizeof(float) * NN;
    float* advv  = (float*)w;   w += sizeof(float) * NN;
    int* offs    = (int*)w;     w += sizeof(int) * (NN + 1);
    int* csr     = (int*)w;     w += sizeof(int) * (size_t)NE;
    int2* ebuf   = (int2*)w;    w += sizeof(int2) * (size_t)NE;
    int* gcnt    = (int*)w;     w += sizeof(int) * NBK;
    int* gbase   = (int*)w;     w += sizeof(int) * NBK;
    int* gcur    = (int*)w;     w += sizeof(int) * NBK;

    const int GB = (NN + 255) / 256;   // BN=256 -> 391 blocks

    // CSR build (bucketed counting sort; shared across all 3 layers)
    hipMemsetAsync(gcnt, 0, sizeof(int) * NBK, stream);
    bucket_hist<<<NBLK, 256, 0, stream>>>(dstp, gcnt);
    bucket_scan<<<1, 512, 0, stream>>>(gcnt, gbase, gcur);
    bin_edges<<<NBLK, 256, 0, stream>>>(srcp, dstp, gcur, ebuf);
    bucket_csr<<<NBK, 256, 0, stream>>>(ebuf, gbase, gcnt, offs, csr);

    // layer 1
    rb_gemm3<NF, HD, 8, 8><<<GB, 256, 0, stream>>>(x, W1, as1, ad1, h, asv, advv);
    gat_agg<HD, true><<<NN / 4, 256, 0, stream>>>(h, asv, advv, offs, csr, b1, featB);

    // layer 2
    rb_gemm3<HD, HD, 8, 8><<<GB, 256, 0, stream>>>(featB, W2, as2, ad2, h, asv, advv);
    gat_agg<HD, true><<<NN / 4, 256, 0, stream>>>(h, asv, advv, offs, csr, b2, featB);

    // layer 3
    rb_gemm3<HD, NC, 4, 8><<<GB, 256, 0, stream>>>(featB, W3, as3, ad3, h, asv, advv);
    gat_agg<NC, false><<<NN / 4, 256, 0, stream>>>(h, asv, advv, offs, csr, b3, out);
}

// Round 4
// 488.241 us; speedup vs baseline: 1.0316x; 1.0248x over previous
//
#include <hip/hip_runtime.h>

#define NN 100000
#define NE 1600000
#define NF 256
#define HD 64
#define NC 32

#define BKS 8
#define NBK ((NN + 255) >> 8)      // 391 buckets of 256 nodes
#define CHUNK 4096                 // edges per bin_edges block
#define NBLK ((NE + CHUNK - 1) / CHUNK)  // 391

__device__ __forceinline__ float lrelu02(float x) { return fmaxf(x, 0.2f * x); }

// ---------------- CSR build via bucketed counting sort (unchanged) ----------------

__global__ __launch_bounds__(256) void bucket_hist(const int* __restrict__ dst, int* __restrict__ gcnt) {
    __shared__ int hist[NBK];
    int tid = threadIdx.x;
    for (int i = tid; i < NBK; i += 256) hist[i] = 0;
    __syncthreads();
    int base = blockIdx.x * CHUNK;
    #pragma unroll
    for (int k = 0; k < CHUNK / 256; k++) {
        int i = base + k * 256 + tid;
        if (i < NE) atomicAdd(&hist[dst[i] >> BKS], 1);
    }
    __syncthreads();
    for (int i = tid; i < NBK; i += 256) if (hist[i]) atomicAdd(&gcnt[i], hist[i]);
}

__global__ void bucket_scan(const int* __restrict__ gcnt, int* __restrict__ gbase, int* __restrict__ gcur) {
    __shared__ int sh[512];
    int tid = threadIdx.x;
    int v = (tid < NBK) ? gcnt[tid] : 0;
    sh[tid] = v;
    __syncthreads();
    for (int d = 1; d < 512; d <<= 1) {
        int t = (tid >= d) ? sh[tid - d] : 0;
        __syncthreads();
        sh[tid] += t;
        __syncthreads();
    }
    if (tid < NBK) { int ex = sh[tid] - v; gbase[tid] = ex; gcur[tid] = ex; }
}

__global__ __launch_bounds__(256) void bin_edges(const int* __restrict__ src, const int* __restrict__ dst,
                                                 int* __restrict__ gcur, int2* __restrict__ ebuf) {
    __shared__ int hist[NBK];
    __shared__ int excl[NBK];
    __shared__ int runbase[NBK];
    __shared__ int ssum[256];
    __shared__ int2 sorted[CHUNK];   // 32 KB
    int tid = threadIdx.x;
    int base = blockIdx.x * CHUNK;
    int n = NE - base; if (n > CHUNK) n = CHUNK;

    for (int i = tid; i < NBK; i += 256) hist[i] = 0;
    __syncthreads();

    int2 ed[CHUNK / 256];
    int bk[CHUNK / 256];
    #pragma unroll
    for (int k = 0; k < CHUNK / 256; k++) {
        int i = base + k * 256 + tid;
        if (i < NE) {
            ed[k] = make_int2(src[i], dst[i]);
            bk[k] = ed[k].y >> BKS;
            atomicAdd(&hist[bk[k]], 1);
        } else bk[k] = -1;
    }
    __syncthreads();
    int h0 = (2 * tid < NBK) ? hist[2 * tid] : 0;
    int h1 = (2 * tid + 1 < NBK) ? hist[2 * tid + 1] : 0;
    ssum[tid] = h0 + h1;
    __syncthreads();
    for (int d = 1; d < 256; d <<= 1) {
        int t = (tid >= d) ? ssum[tid - d] : 0;
        __syncthreads();
        ssum[tid] += t;
        __syncthreads();
    }
    int pref = ssum[tid] - (h0 + h1);
    if (2 * tid < NBK) excl[2 * tid] = pref;
    if (2 * tid + 1 < NBK) excl[2 * tid + 1] = pref + h0;
    for (int b = tid; b < NBK; b += 256) {
        int c = hist[b];
        runbase[b] = c ? atomicAdd(&gcur[b], c) : 0;
    }
    __syncthreads();
    #pragma unroll
    for (int k = 0; k < CHUNK / 256; k++) {
        if (bk[k] >= 0) {
            int r = atomicAdd(&excl[bk[k]], 1);
            sorted[r] = ed[k];
        }
    }
    __syncthreads();
    for (int i = tid; i < n; i += 256) {
        int2 e = sorted[i];
        int b = e.y >> BKS;
        int local_rank = i - (excl[b] - hist[b]);
        ebuf[runbase[b] + local_rank] = e;
    }
}

__global__ __launch_bounds__(256) void bucket_csr(const int2* __restrict__ ebuf, const int* __restrict__ gbase,
                                                  const int* __restrict__ gcnt,
                                                  int* __restrict__ offs, int* __restrict__ csr) {
    __shared__ int hist[256], cur[256], ssum[256];
    int b = blockIdx.x, tid = threadIdx.x;
    int ebeg = gbase[b], cnt = gcnt[b];
    int node0 = b << BKS;
    hist[tid] = 0;
    __syncthreads();
    for (int i = ebeg + tid; i < ebeg + cnt; i += 256)
        atomicAdd(&hist[ebuf[i].y & 255], 1);
    __syncthreads();
    int v = hist[tid];
    ssum[tid] = v;
    __syncthreads();
    for (int d = 1; d < 256; d <<= 1) {
        int t = (tid >= d) ? ssum[tid - d] : 0;
        __syncthreads();
        ssum[tid] += t;
        __syncthreads();
    }
    int ex = ebeg + ssum[tid] - v;
    cur[tid] = ex;
    int nnode = NN - node0; if (nnode > 256) nnode = 256;
    if (tid < nnode) offs[node0 + tid] = ex;
    if (b == NBK - 1 && tid == nnode - 1) offs[NN] = ebeg + cnt;
    __syncthreads();
    for (int i = ebeg + tid; i < ebeg + cnt; i += 256) {
        int2 e = ebuf[i];
        int pos = atomicAdd(&cur[e.y & 255], 1);
        csr[pos] = e.x;
    }
}

// ---------------- double-buffered register-blocked GEMM (R0 tile + T14 pipeline) ----------------
// R0 geometry: BN=128 (CG=8) / BN=256 (CG=4), 4 nodes x 8 cols per thread, KC=32.
// Pipeline: at chunk t, issue chunk t+1's global loads into registers; compute chunk t
// while loads are in flight; ds_write regs -> alternate LDS buffer AFTER compute
// (vmcnt wait lands post-compute); ONE barrier per chunk. Hides HBM/L2 latency that
// the old stage->barrier->compute structure exposed (m233-style stall).

template <int CIN, int COUT, int CG>
__global__ __launch_bounds__(256) void rb_gemm4(const float* __restrict__ in, const float* __restrict__ W,
                                                const float* __restrict__ a_s, const float* __restrict__ a_d,
                                                float* __restrict__ h, float* __restrict__ asv,
                                                float* __restrict__ adv) {
    const int KC  = 32;
    const int NG  = 256 / CG;
    const int BN  = NG * 4;          // 128 (CG=8) or 256 (CG=4)
    const int BNP = BN + 4;
    const int NCH = CIN / KC;
    const int XPT = BN * KC / 4 / 256;            // float4 x-loads per thread: 4 or 8
    const int WF4 = KC * COUT / 4;                // total W float4s per chunk
    const int WPT = (WF4 + 255) / 256;            // 2 (COUT=64) or 1 (COUT=32)
    __shared__ float xsT[2][KC * BNP];
    __shared__ float Wl[2][KC * COUT];

    int tid = threadIdx.x;
    int cg = tid % CG;
    int ng = tid / CG;
    int c0 = cg * 8;
    int n0base = blockIdx.x * BN;

    float4 xr[XPT];
    float4 wr[WPT];

    // chunk-t global loads into registers (issued early; latency hides under compute)
    auto load_regs = [&](int k0) {
        #pragma unroll
        for (int i = 0; i < XPT; i++) {
            int f = tid + i * 256;
            int n = f >> 3, q = f & 7;
            int gn = n0base + n;
            xr[i] = make_float4(0.f, 0.f, 0.f, 0.f);
            if (gn < NN) xr[i] = *(const float4*)&in[(size_t)gn * CIN + k0 + q * 4];
        }
        #pragma unroll
        for (int i = 0; i < WPT; i++) {
            int f = tid + i * 256;
            if (f < WF4) wr[i] = *(const float4*)&W[(size_t)k0 * COUT + f * 4];
        }
    };
    // register -> LDS (transposed scatter for x); vmcnt wait naturally lands here
    auto write_lds = [&](int buf) {
        #pragma unroll
        for (int i = 0; i < XPT; i++) {
            int f = tid + i * 256;
            int n = f >> 3, q = f & 7;
            float* p = &xsT[buf][0];
            p[(q * 4 + 0) * BNP + n] = xr[i].x;
            p[(q * 4 + 1) * BNP + n] = xr[i].y;
            p[(q * 4 + 2) * BNP + n] = xr[i].z;
            p[(q * 4 + 3) * BNP + n] = xr[i].w;
        }
        #pragma unroll
        for (int i = 0; i < WPT; i++) {
            int f = tid + i * 256;
            if (f < WF4) *(float4*)&Wl[buf][f * 4] = wr[i];
        }
    };

    float4 a0[4], a1[4];
    #pragma unroll
    for (int i = 0; i < 4; i++) { a0[i] = make_float4(0,0,0,0); a1[i] = make_float4(0,0,0,0); }

    // prologue: stage chunk 0
    load_regs(0);
    write_lds(0);
    __syncthreads();

    for (int t = 0; t < NCH; t++) {
        int cur = t & 1;
        if (t + 1 < NCH) load_regs((t + 1) * KC);   // in flight during compute
        #pragma unroll 4
        for (int k = 0; k < KC; k++) {
            float4 xv = *(const float4*)&xsT[cur][k * BNP + ng * 4];
            float4 w0 = *(const float4*)&Wl[cur][k * COUT + c0];
            float4 w1 = *(const float4*)&Wl[cur][k * COUT + c0 + 4];
            #pragma unroll
            for (int i = 0; i < 4; i++) {
                float xc = (i == 0) ? xv.x : (i == 1) ? xv.y : (i == 2) ? xv.z : xv.w;
                a0[i].x += xc * w0.x; a0[i].y += xc * w0.y; a0[i].z += xc * w0.z; a0[i].w += xc * w0.w;
                a1[i].x += xc * w1.x; a1[i].y += xc * w1.y; a1[i].z += xc * w1.z; a1[i].w += xc * w1.w;
            }
        }
        if (t + 1 < NCH) {
            write_lds(cur ^ 1);      // waits vmcnt here, after compute
            __syncthreads();
        }
    }

    // epilogue (R0): h store + a_s/a_d dots, shfl-reduce across CG col-groups
    float4 As0 = *(const float4*)&a_s[c0];
    float4 As1 = *(const float4*)&a_s[c0 + 4];
    float4 Ad0 = *(const float4*)&a_d[c0];
    float4 Ad1 = *(const float4*)&a_d[c0 + 4];
    #pragma unroll
    for (int i = 0; i < 4; i++) {
        int n = n0base + ng * 4 + i;
        if (n < NN) {
            *(float4*)&h[(size_t)n * COUT + c0] = a0[i];
            *(float4*)&h[(size_t)n * COUT + c0 + 4] = a1[i];
        }
        float vs = a0[i].x * As0.x + a0[i].y * As0.y + a0[i].z * As0.z + a0[i].w * As0.w
                 + a1[i].x * As1.x + a1[i].y * As1.y + a1[i].z * As1.z + a1[i].w * As1.w;
        float vd = a0[i].x * Ad0.x + a0[i].y * Ad0.y + a0[i].z * Ad0.z + a0[i].w * Ad0.w
                 + a1[i].x * Ad1.x + a1[i].y * Ad1.y + a1[i].z * Ad1.z + a1[i].w * Ad1.w;
        #pragma unroll
        for (int off = 1; off < CG; off <<= 1) { vs += __shfl_xor(vs, off); vd += __shfl_xor(vd, off); }
        if (cg == 0 && n < NN) { asv[n] = vs; adv[n] = vd; }
    }
}

// ---------------- fused aggregate (unchanged) ----------------

template <int C, bool ACT>
__global__ __launch_bounds__(256) void gat_agg(const float* __restrict__ h, const float* __restrict__ asv,
                                               const float* __restrict__ adv, const int* __restrict__ offs,
                                               const int* __restrict__ csr,
                                               const float* __restrict__ bias, float* __restrict__ out) {
    const int LPR = C / 4;
    const int G = 64 / LPR;
    const float4* h4 = (const float4*)h;
    int lane = threadIdx.x & 63;
    int v = blockIdx.x * 4 + (threadIdx.x >> 6);
    int beg = offs[v], end = offs[v + 1];
    int g = lane / LPR, r = lane % LPR;
    float adv_v = adv[v];

    float4 acc = {0.f, 0.f, 0.f, 0.f};
    float dsum = 0.f;
    #pragma unroll 4
    for (int e = beg + g; e < end; e += G) {
        int s = csr[e];
        float ww = __expf(lrelu02(asv[s] + adv_v));
        float4 hv = h4[(size_t)s * LPR + r];
        dsum += ww;
        acc.x += ww * hv.x; acc.y += ww * hv.y; acc.z += ww * hv.z; acc.w += ww * hv.w;
    }
    #pragma unroll
    for (int off = LPR; off < 64; off <<= 1) {
        acc.x += __shfl_xor(acc.x, off);
        acc.y += __shfl_xor(acc.y, off);
        acc.z += __shfl_xor(acc.z, off);
        acc.w += __shfl_xor(acc.w, off);
        dsum += __shfl_xor(dsum, off);
    }
    if (g == 0) {
        float selfw = __expf(lrelu02(asv[v] + adv_v));
        float4 hs = h4[(size_t)v * LPR + r];
        acc.x += selfw * hs.x; acc.y += selfw * hs.y;
        acc.z += selfw * hs.z; acc.w += selfw * hs.w;
        dsum += selfw;
        float inv = 1.f / (dsum + 1e-16f);
        float4 bb = ((const float4*)bias)[r];
        float4 o;
        o.x = acc.x * inv + bb.x; o.y = acc.y * inv + bb.y;
        o.z = acc.z * inv + bb.z; o.w = acc.w * inv + bb.w;
        if (ACT) {
            o.x = fmaxf(o.x, 0.01f * o.x); o.y = fmaxf(o.y, 0.01f * o.y);
            o.z = fmaxf(o.z, 0.01f * o.z); o.w = fmaxf(o.w, 0.01f * o.w);
        }
        ((float4*)out)[(size_t)v * LPR + r] = o;
    }
}

// ---------------- launch ----------------

extern "C" void kernel_launch(void* const* d_in, const int* in_sizes, int n_in,
                              void* d_out, int out_size, void* d_ws, size_t ws_size,
                              hipStream_t stream) {
    const float* x   = (const float*)d_in[0];
    const int*   ei  = (const int*)d_in[1];
    const float* W1  = (const float*)d_in[2];
    const float* as1 = (const float*)d_in[3];
    const float* ad1 = (const float*)d_in[4];
    const float* b1  = (const float*)d_in[5];
    const float* W2  = (const float*)d_in[6];
    const float* as2 = (const float*)d_in[7];
    const float* ad2 = (const float*)d_in[8];
    const float* b2  = (const float*)d_in[9];
    const float* W3  = (const float*)d_in[10];
    const float* as3 = (const float*)d_in[11];
    const float* ad3 = (const float*)d_in[12];
    const float* b3  = (const float*)d_in[13];
    float* out = (float*)d_out;

    const int* srcp = ei;
    const int* dstp = ei + NE;

    char* w = (char*)d_ws;
    float* h     = (float*)w;   w += sizeof(float) * (size_t)NN * HD;
    float* featB = (float*)w;   w += sizeof(float) * (size_t)NN * HD;
    float* asv   = (float*)w;   w += sizeof(float) * NN;
    float* advv  = (float*)w;   w += sizeof(float) * NN;
    int* offs    = (int*)w;     w += sizeof(int) * (NN + 1);
    int* csr     = (int*)w;     w += sizeof(int) * (size_t)NE;
    int2* ebuf   = (int2*)w;    w += sizeof(int2) * (size_t)NE;
    int* gcnt    = (int*)w;     w += sizeof(int) * NBK;
    int* gbase   = (int*)w;     w += sizeof(int) * NBK;
    int* gcur    = (int*)w;     w += sizeof(int) * NBK;

    const int GB64 = (NN + 127) / 128;   // CG=8 -> BN=128 -> 782 blocks
    const int GB32 = (NN + 255) / 256;   // CG=4 -> BN=256 -> 391 blocks

    // CSR build (bucketed counting sort; shared across all 3 layers)
    hipMemsetAsync(gcnt, 0, sizeof(int) * NBK, stream);
    bucket_hist<<<NBLK, 256, 0, stream>>>(dstp, gcnt);
    bucket_scan<<<1, 512, 0, stream>>>(gcnt, gbase, gcur);
    bin_edges<<<NBLK, 256, 0, stream>>>(srcp, dstp, gcur, ebuf);
    bucket_csr<<<NBK, 256, 0, stream>>>(ebuf, gbase, gcnt, offs, csr);

    // layer 1
    rb_gemm4<NF, HD, 8><<<GB64, 256, 0, stream>>>(x, W1, as1, ad1, h, asv, advv);
    gat_agg<HD, true><<<NN / 4, 256, 0, stream>>>(h, asv, advv, offs, csr, b1, featB);

    // layer 2
    rb_gemm4<HD, HD, 8><<<GB64, 256, 0, stream>>>(featB, W2, as2, ad2, h, asv, advv);
    gat_agg<HD, true><<<NN / 4, 256, 0, stream>>>(h, asv, advv, offs, csr, b2, featB);

    // layer 3
    rb_gemm4<HD, NC, 4><<<GB32, 256, 0, stream>>>(featB, W3, as3, ad3, h, asv, advv);
    gat_agg<NC, false><<<NN / 4, 256, 0, stream>>>(h, asv, advv, offs, csr, b3, out);
}

// Round 5
// 461.176 us; speedup vs baseline: 1.0921x; 1.0587x over previous
//
#include <hip/hip_runtime.h>

#define NN 100000
#define NE 1600000
#define NF 256
#define HD 64
#define NC 32

#define BKS 8
#define NBK ((NN + 255) >> 8)      // 391 buckets of 256 nodes
#define CHUNK 4096                 // edges per bin_edges block
#define NBLK ((NE + CHUNK - 1) / CHUNK)  // 391

__device__ __forceinline__ float lrelu02(float x) { return fmaxf(x, 0.2f * x); }

typedef __attribute__((ext_vector_type(8))) short bf16x8;
typedef __attribute__((ext_vector_type(4))) float f32x4;

// round-to-nearest-even f32 -> bf16 (finite inputs)
__device__ __forceinline__ unsigned short f2bf(float f) {
    unsigned int u = __float_as_uint(f);
    unsigned int r = u + 0x7FFFu + ((u >> 16) & 1u);
    return (unsigned short)(r >> 16);
}
__device__ __forceinline__ float bf2f(unsigned short s) {
    return __uint_as_float(((unsigned int)s) << 16);
}

// ---------------- CSR build via bucketed counting sort (unchanged) ----------------

__global__ __launch_bounds__(256) void bucket_hist(const int* __restrict__ dst, int* __restrict__ gcnt) {
    __shared__ int hist[NBK];
    int tid = threadIdx.x;
    for (int i = tid; i < NBK; i += 256) hist[i] = 0;
    __syncthreads();
    int base = blockIdx.x * CHUNK;
    #pragma unroll
    for (int k = 0; k < CHUNK / 256; k++) {
        int i = base + k * 256 + tid;
        if (i < NE) atomicAdd(&hist[dst[i] >> BKS], 1);
    }
    __syncthreads();
    for (int i = tid; i < NBK; i += 256) if (hist[i]) atomicAdd(&gcnt[i], hist[i]);
}

__global__ void bucket_scan(const int* __restrict__ gcnt, int* __restrict__ gbase, int* __restrict__ gcur) {
    __shared__ int sh[512];
    int tid = threadIdx.x;
    int v = (tid < NBK) ? gcnt[tid] : 0;
    sh[tid] = v;
    __syncthreads();
    for (int d = 1; d < 512; d <<= 1) {
        int t = (tid >= d) ? sh[tid - d] : 0;
        __syncthreads();
        sh[tid] += t;
        __syncthreads();
    }
    if (tid < NBK) { int ex = sh[tid] - v; gbase[tid] = ex; gcur[tid] = ex; }
}

__global__ __launch_bounds__(256) void bin_edges(const int* __restrict__ src, const int* __restrict__ dst,
                                                 int* __restrict__ gcur, int2* __restrict__ ebuf) {
    __shared__ int hist[NBK];
    __shared__ int excl[NBK];
    __shared__ int runbase[NBK];
    __shared__ int ssum[256];
    __shared__ int2 sorted[CHUNK];   // 32 KB
    int tid = threadIdx.x;
    int base = blockIdx.x * CHUNK;
    int n = NE - base; if (n > CHUNK) n = CHUNK;

    for (int i = tid; i < NBK; i += 256) hist[i] = 0;
    __syncthreads();

    int2 ed[CHUNK / 256];
    int bk[CHUNK / 256];
    #pragma unroll
    for (int k = 0; k < CHUNK / 256; k++) {
        int i = base + k * 256 + tid;
        if (i < NE) {
            ed[k] = make_int2(src[i], dst[i]);
            bk[k] = ed[k].y >> BKS;
            atomicAdd(&hist[bk[k]], 1);
        } else bk[k] = -1;
    }
    __syncthreads();
    int h0 = (2 * tid < NBK) ? hist[2 * tid] : 0;
    int h1 = (2 * tid + 1 < NBK) ? hist[2 * tid + 1] : 0;
    ssum[tid] = h0 + h1;
    __syncthreads();
    for (int d = 1; d < 256; d <<= 1) {
        int t = (tid >= d) ? ssum[tid - d] : 0;
        __syncthreads();
        ssum[tid] += t;
        __syncthreads();
    }
    int pref = ssum[tid] - (h0 + h1);
    if (2 * tid < NBK) excl[2 * tid] = pref;
    if (2 * tid + 1 < NBK) excl[2 * tid + 1] = pref + h0;
    for (int b = tid; b < NBK; b += 256) {
        int c = hist[b];
        runbase[b] = c ? atomicAdd(&gcur[b], c) : 0;
    }
    __syncthreads();
    #pragma unroll
    for (int k = 0; k < CHUNK / 256; k++) {
        if (bk[k] >= 0) {
            int r = atomicAdd(&excl[bk[k]], 1);
            sorted[r] = ed[k];
        }
    }
    __syncthreads();
    for (int i = tid; i < n; i += 256) {
        int2 e = sorted[i];
        int b = e.y >> BKS;
        int local_rank = i - (excl[b] - hist[b]);
        ebuf[runbase[b] + local_rank] = e;
    }
}

__global__ __launch_bounds__(256) void bucket_csr(const int2* __restrict__ ebuf, const int* __restrict__ gbase,
                                                  const int* __restrict__ gcnt,
                                                  int* __restrict__ offs, int* __restrict__ csr) {
    __shared__ int hist[256], cur[256], ssum[256];
    int b = blockIdx.x, tid = threadIdx.x;
    int ebeg = gbase[b], cnt = gcnt[b];
    int node0 = b << BKS;
    hist[tid] = 0;
    __syncthreads();
    for (int i = ebeg + tid; i < ebeg + cnt; i += 256)
        atomicAdd(&hist[ebuf[i].y & 255], 1);
    __syncthreads();
    int v = hist[tid];
    ssum[tid] = v;
    __syncthreads();
    for (int d = 1; d < 256; d <<= 1) {
        int t = (tid >= d) ? ssum[tid - d] : 0;
        __syncthreads();
        ssum[tid] += t;
        __syncthreads();
    }
    int ex = ebeg + ssum[tid] - v;
    cur[tid] = ex;
    int nnode = NN - node0; if (nnode > 256) nnode = 256;
    if (tid < nnode) offs[node0 + tid] = ex;
    if (b == NBK - 1 && tid == nnode - 1) offs[NN] = ebeg + cnt;
    __syncthreads();
    for (int i = ebeg + tid; i < ebeg + cnt; i += 256) {
        int2 e = ebuf[i];
        int pos = atomicAdd(&cur[e.y & 255], 1);
        csr[pos] = e.x;
    }
}

// ---------------- split-bf16 MFMA GEMM ----------------
// h = x @ W via 3-term bf16 split: x=xh+xl, W=wh+wl; h ~= xh*wh + xh*wl + xl*wh
// (dropped xl*wl ~ 2^-18 relative). 16x16x32 bf16 MFMA, C/D layout per guide
// (col=lane&15, row=(lane>>4)*4+reg; A/B frags: lane&15 = free dim, lane>>4 = k-group,
// 8 contiguous k per lane; D = A * B^T with B stored [col][k]).
// Block: 128 rows x COUT cols, 4 waves; wave = 32 rows = 2 row-tiles. KC=32.
// LDS tiles hi/lo with row-stride RS=40 bf16 (80 B: 16B-aligned rows, uniform banks).

template <int CIN, int COUT>
__global__ __launch_bounds__(256) void mfma_gemm(const float* __restrict__ in, const float* __restrict__ W,
                                                 const float* __restrict__ a_s, const float* __restrict__ a_d,
                                                 float* __restrict__ h, float* __restrict__ asv,
                                                 float* __restrict__ adv) {
    const int KC  = 32;
    const int BM  = 128;
    const int RS  = 40;              // bf16 elems per LDS row (pad from 32)
    const int NCT = COUT / 16;       // col tiles: 4 (COUT=64) or 2 (COUT=32)
    const int NCH = CIN / KC;
    __shared__ unsigned short Ah[BM * RS];     // 10 KB
    __shared__ unsigned short Al[BM * RS];     // 10 KB
    __shared__ unsigned short Bh[COUT * RS];   // 5 / 2.5 KB
    __shared__ unsigned short Bl[COUT * RS];

    int tid = threadIdx.x;
    int lane = tid & 63;
    int wave = tid >> 6;
    int fr = lane & 15;              // free-dim index within 16-tile
    int kg = lane >> 4;              // k-group (0..3), 8 k each
    int n0base = blockIdx.x * BM;

    f32x4 acc[2][NCT];
    #pragma unroll
    for (int rt = 0; rt < 2; rt++)
        #pragma unroll
        for (int ct = 0; ct < NCT; ct++) acc[rt][ct] = (f32x4){0.f, 0.f, 0.f, 0.f};

    for (int t = 0; t < NCH; t++) {
        int k0 = t * KC;
        __syncthreads();
        // ---- stage x -> Ah/Al (split bf16), coalesced float4 reads ----
        unsigned int* Ahu = (unsigned int*)Ah;
        unsigned int* Alu = (unsigned int*)Al;
        #pragma unroll
        for (int f = tid; f < BM * KC / 4; f += 256) {
            int row = f >> 3;            // KC/4 = 8 float4 per row
            int q = f & 7;
            int gn = n0base + row;
            float4 v = make_float4(0.f, 0.f, 0.f, 0.f);
            if (gn < NN) v = *(const float4*)&in[(size_t)gn * CIN + k0 + q * 4];
            unsigned short h0 = f2bf(v.x), h1 = f2bf(v.y), h2 = f2bf(v.z), h3 = f2bf(v.w);
            unsigned short l0 = f2bf(v.x - bf2f(h0)), l1 = f2bf(v.y - bf2f(h1));
            unsigned short l2 = f2bf(v.z - bf2f(h2)), l3 = f2bf(v.w - bf2f(h3));
            int wi = row * (RS / 2) + q * 2;         // uint index (RS/2=20 uints per row)
            Ahu[wi]     = (unsigned int)h0 | ((unsigned int)h1 << 16);
            Ahu[wi + 1] = (unsigned int)h2 | ((unsigned int)h3 << 16);
            Alu[wi]     = (unsigned int)l0 | ((unsigned int)l1 << 16);
            Alu[wi + 1] = (unsigned int)l2 | ((unsigned int)l3 << 16);
        }
        // ---- stage W -> Bh/Bl transposed [col][k] (split bf16) ----
        #pragma unroll
        for (int f = tid; f < KC * COUT / 4; f += 256) {
            int k = f / (COUT / 4);
            int c = (f % (COUT / 4)) * 4;
            float4 v = *(const float4*)&W[(size_t)(k0 + k) * COUT + c];
            unsigned short h0 = f2bf(v.x), h1 = f2bf(v.y), h2 = f2bf(v.z), h3 = f2bf(v.w);
            Bh[(c + 0) * RS + k] = h0;  Bl[(c + 0) * RS + k] = f2bf(v.x - bf2f(h0));
            Bh[(c + 1) * RS + k] = h1;  Bl[(c + 1) * RS + k] = f2bf(v.y - bf2f(h1));
            Bh[(c + 2) * RS + k] = h2;  Bl[(c + 2) * RS + k] = f2bf(v.z - bf2f(h2));
            Bh[(c + 3) * RS + k] = h3;  Bl[(c + 3) * RS + k] = f2bf(v.w - bf2f(h3));
        }
        __syncthreads();
        // ---- fragments + MFMA ----
        bf16x8 ah[2], al[2], bh[NCT], bl[NCT];
        #pragma unroll
        for (int rt = 0; rt < 2; rt++) {
            int row = wave * 32 + rt * 16 + fr;
            ah[rt] = *(const bf16x8*)&Ah[row * RS + kg * 8];
            al[rt] = *(const bf16x8*)&Al[row * RS + kg * 8];
        }
        #pragma unroll
        for (int ct = 0; ct < NCT; ct++) {
            int col = ct * 16 + fr;
            bh[ct] = *(const bf16x8*)&Bh[col * RS + kg * 8];
            bl[ct] = *(const bf16x8*)&Bl[col * RS + kg * 8];
        }
        #pragma unroll
        for (int rt = 0; rt < 2; rt++)
            #pragma unroll
            for (int ct = 0; ct < NCT; ct++) {
                acc[rt][ct] = __builtin_amdgcn_mfma_f32_16x16x32_bf16(ah[rt], bh[ct], acc[rt][ct], 0, 0, 0);
                acc[rt][ct] = __builtin_amdgcn_mfma_f32_16x16x32_bf16(ah[rt], bl[ct], acc[rt][ct], 0, 0, 0);
                acc[rt][ct] = __builtin_amdgcn_mfma_f32_16x16x32_bf16(al[rt], bh[ct], acc[rt][ct], 0, 0, 0);
            }
    }

    // ---- epilogue: h store + fused a_s/a_d dots (16-lane shfl reduce) ----
    float As_l[NCT], Ad_l[NCT];
    #pragma unroll
    for (int ct = 0; ct < NCT; ct++) {
        As_l[ct] = a_s[ct * 16 + fr];
        Ad_l[ct] = a_d[ct * 16 + fr];
    }
    #pragma unroll
    for (int rt = 0; rt < 2; rt++) {
        #pragma unroll
        for (int r = 0; r < 4; r++) {
            int row = n0base + wave * 32 + rt * 16 + kg * 4 + r;
            if (row < NN) {
                #pragma unroll
                for (int ct = 0; ct < NCT; ct++)
                    h[(size_t)row * COUT + ct * 16 + fr] = acc[rt][ct][r];
            }
            float ps = 0.f, pd = 0.f;
            #pragma unroll
            for (int ct = 0; ct < NCT; ct++) {
                ps += acc[rt][ct][r] * As_l[ct];
                pd += acc[rt][ct][r] * Ad_l[ct];
            }
            #pragma unroll
            for (int off = 1; off < 16; off <<= 1) {
                ps += __shfl_xor(ps, off);
                pd += __shfl_xor(pd, off);
            }
            if (fr == 0 && row < NN) { asv[row] = ps; adv[row] = pd; }
        }
    }
}

// ---------------- fused aggregate (unchanged) ----------------

template <int C, bool ACT>
__global__ __launch_bounds__(256) void gat_agg(const float* __restrict__ h, const float* __restrict__ asv,
                                               const float* __restrict__ adv, const int* __restrict__ offs,
                                               const int* __restrict__ csr,
                                               const float* __restrict__ bias, float* __restrict__ out) {
    const int LPR = C / 4;
    const int G = 64 / LPR;
    const float4* h4 = (const float4*)h;
    int lane = threadIdx.x & 63;
    int v = blockIdx.x * 4 + (threadIdx.x >> 6);
    int beg = offs[v], end = offs[v + 1];
    int g = lane / LPR, r = lane % LPR;
    float adv_v = adv[v];

    float4 acc = {0.f, 0.f, 0.f, 0.f};
    float dsum = 0.f;
    #pragma unroll 4
    for (int e = beg + g; e < end; e += G) {
        int s = csr[e];
        float ww = __expf(lrelu02(asv[s] + adv_v));
        float4 hv = h4[(size_t)s * LPR + r];
        dsum += ww;
        acc.x += ww * hv.x; acc.y += ww * hv.y; acc.z += ww * hv.z; acc.w += ww * hv.w;
    }
    #pragma unroll
    for (int off = LPR; off < 64; off <<= 1) {
        acc.x += __shfl_xor(acc.x, off);
        acc.y += __shfl_xor(acc.y, off);
        acc.z += __shfl_xor(acc.z, off);
        acc.w += __shfl_xor(acc.w, off);
        dsum += __shfl_xor(dsum, off);
    }
    if (g == 0) {
        float selfw = __expf(lrelu02(asv[v] + adv_v));
        float4 hs = h4[(size_t)v * LPR + r];
        acc.x += selfw * hs.x; acc.y += selfw * hs.y;
        acc.z += selfw * hs.z; acc.w += selfw * hs.w;
        dsum += selfw;
        float inv = 1.f / (dsum + 1e-16f);
        float4 bb = ((const float4*)bias)[r];
        float4 o;
        o.x = acc.x * inv + bb.x; o.y = acc.y * inv + bb.y;
        o.z = acc.z * inv + bb.z; o.w = acc.w * inv + bb.w;
        if (ACT) {
            o.x = fmaxf(o.x, 0.01f * o.x); o.y = fmaxf(o.y, 0.01f * o.y);
            o.z = fmaxf(o.z, 0.01f * o.z); o.w = fmaxf(o.w, 0.01f * o.w);
        }
        ((float4*)out)[(size_t)v * LPR + r] = o;
    }
}

// ---------------- launch ----------------

extern "C" void kernel_launch(void* const* d_in, const int* in_sizes, int n_in,
                              void* d_out, int out_size, void* d_ws, size_t ws_size,
                              hipStream_t stream) {
    const float* x   = (const float*)d_in[0];
    const int*   ei  = (const int*)d_in[1];
    const float* W1  = (const float*)d_in[2];
    const float* as1 = (const float*)d_in[3];
    const float* ad1 = (const float*)d_in[4];
    const float* b1  = (const float*)d_in[5];
    const float* W2  = (const float*)d_in[6];
    const float* as2 = (const float*)d_in[7];
    const float* ad2 = (const float*)d_in[8];
    const float* b2  = (const float*)d_in[9];
    const float* W3  = (const float*)d_in[10];
    const float* as3 = (const float*)d_in[11];
    const float* ad3 = (const float*)d_in[12];
    const float* b3  = (const float*)d_in[13];
    float* out = (float*)d_out;

    const int* srcp = ei;
    const int* dstp = ei + NE;

    char* w = (char*)d_ws;
    float* h     = (float*)w;   w += sizeof(float) * (size_t)NN * HD;
    float* featB = (float*)w;   w += sizeof(float) * (size_t)NN * HD;
    float* asv   = (float*)w;   w += sizeof(float) * NN;
    float* advv  = (float*)w;   w += sizeof(float) * NN;
    int* offs    = (int*)w;     w += sizeof(int) * (NN + 1);
    int* csr     = (int*)w;     w += sizeof(int) * (size_t)NE;
    int2* ebuf   = (int2*)w;    w += sizeof(int2) * (size_t)NE;
    int* gcnt    = (int*)w;     w += sizeof(int) * NBK;
    int* gbase   = (int*)w;     w += sizeof(int) * NBK;
    int* gcur    = (int*)w;     w += sizeof(int) * NBK;

    const int GBM = (NN + 127) / 128;   // 782 blocks

    // CSR build (bucketed counting sort; shared across all 3 layers)
    hipMemsetAsync(gcnt, 0, sizeof(int) * NBK, stream);
    bucket_hist<<<NBLK, 256, 0, stream>>>(dstp, gcnt);
    bucket_scan<<<1, 512, 0, stream>>>(gcnt, gbase, gcur);
    bin_edges<<<NBLK, 256, 0, stream>>>(srcp, dstp, gcur, ebuf);
    bucket_csr<<<NBK, 256, 0, stream>>>(ebuf, gbase, gcnt, offs, csr);

    // layer 1
    mfma_gemm<NF, HD><<<GBM, 256, 0, stream>>>(x, W1, as1, ad1, h, asv, advv);
    gat_agg<HD, true><<<NN / 4, 256, 0, stream>>>(h, asv, advv, offs, csr, b1, featB);

    // layer 2
    mfma_gemm<HD, HD><<<GBM, 256, 0, stream>>>(featB, W2, as2, ad2, h, asv, advv);
    gat_agg<HD, true><<<NN / 4, 256, 0, stream>>>(h, asv, advv, offs, csr, b2, featB);

    // layer 3
    mfma_gemm<HD, NC><<<GBM, 256, 0, stream>>>(featB, W3, as3, ad3, h, asv, advv);
    gat_agg<NC, false><<<NN / 4, 256, 0, stream>>>(h, asv, advv, offs, csr, b3, out);
}

// Round 6
// 454.514 us; speedup vs baseline: 1.1081x; 1.0147x over previous
//
#include <hip/hip_runtime.h>

#define NN 100000
#define NE 1600000
#define NF 256
#define HD 64
#define NC 32

#define BKS 8
#define NBK ((NN + 255) >> 8)      // 391 buckets of 256 nodes
#define CHUNK 4096                 // edges per bin_edges block
#define NBLK ((NE + CHUNK - 1) / CHUNK)  // 391

__device__ __forceinline__ float lrelu02(float x) { return fmaxf(x, 0.2f * x); }

typedef __attribute__((ext_vector_type(8))) short bf16x8;
typedef __attribute__((ext_vector_type(4))) float f32x4;

// round-to-nearest-even f32 -> bf16 (finite inputs)
__device__ __forceinline__ unsigned short f2bf(float f) {
    unsigned int u = __float_as_uint(f);
    unsigned int r = u + 0x7FFFu + ((u >> 16) & 1u);
    return (unsigned short)(r >> 16);
}
__device__ __forceinline__ float bf2f(unsigned short s) {
    return __uint_as_float(((unsigned int)s) << 16);
}
__device__ __forceinline__ void split4(float4 v, uint2& hi, uint2& lo) {
    unsigned short h0 = f2bf(v.x), h1 = f2bf(v.y), h2 = f2bf(v.z), h3 = f2bf(v.w);
    unsigned short l0 = f2bf(v.x - bf2f(h0)), l1 = f2bf(v.y - bf2f(h1));
    unsigned short l2 = f2bf(v.z - bf2f(h2)), l3 = f2bf(v.w - bf2f(h3));
    hi.x = (unsigned int)h0 | ((unsigned int)h1 << 16);
    hi.y = (unsigned int)h2 | ((unsigned int)h3 << 16);
    lo.x = (unsigned int)l0 | ((unsigned int)l1 << 16);
    lo.y = (unsigned int)l2 | ((unsigned int)l3 << 16);
}

// ---------------- CSR build via bucketed counting sort (unchanged) ----------------

__global__ __launch_bounds__(256) void bucket_hist(const int* __restrict__ dst, int* __restrict__ gcnt) {
    __shared__ int hist[NBK];
    int tid = threadIdx.x;
    for (int i = tid; i < NBK; i += 256) hist[i] = 0;
    __syncthreads();
    int base = blockIdx.x * CHUNK;
    #pragma unroll
    for (int k = 0; k < CHUNK / 256; k++) {
        int i = base + k * 256 + tid;
        if (i < NE) atomicAdd(&hist[dst[i] >> BKS], 1);
    }
    __syncthreads();
    for (int i = tid; i < NBK; i += 256) if (hist[i]) atomicAdd(&gcnt[i], hist[i]);
}

__global__ void bucket_scan(const int* __restrict__ gcnt, int* __restrict__ gbase, int* __restrict__ gcur) {
    __shared__ int sh[512];
    int tid = threadIdx.x;
    int v = (tid < NBK) ? gcnt[tid] : 0;
    sh[tid] = v;
    __syncthreads();
    for (int d = 1; d < 512; d <<= 1) {
        int t = (tid >= d) ? sh[tid - d] : 0;
        __syncthreads();
        sh[tid] += t;
        __syncthreads();
    }
    if (tid < NBK) { int ex = sh[tid] - v; gbase[tid] = ex; gcur[tid] = ex; }
}

__global__ __launch_bounds__(256) void bin_edges(const int* __restrict__ src, const int* __restrict__ dst,
                                                 int* __restrict__ gcur, int2* __restrict__ ebuf) {
    __shared__ int hist[NBK];
    __shared__ int excl[NBK];
    __shared__ int runbase[NBK];
    __shared__ int ssum[256];
    __shared__ int2 sorted[CHUNK];   // 32 KB
    int tid = threadIdx.x;
    int base = blockIdx.x * CHUNK;
    int n = NE - base; if (n > CHUNK) n = CHUNK;

    for (int i = tid; i < NBK; i += 256) hist[i] = 0;
    __syncthreads();

    int2 ed[CHUNK / 256];
    int bk[CHUNK / 256];
    #pragma unroll
    for (int k = 0; k < CHUNK / 256; k++) {
        int i = base + k * 256 + tid;
        if (i < NE) {
            ed[k] = make_int2(src[i], dst[i]);
            bk[k] = ed[k].y >> BKS;
            atomicAdd(&hist[bk[k]], 1);
        } else bk[k] = -1;
    }
    __syncthreads();
    int h0 = (2 * tid < NBK) ? hist[2 * tid] : 0;
    int h1 = (2 * tid + 1 < NBK) ? hist[2 * tid + 1] : 0;
    ssum[tid] = h0 + h1;
    __syncthreads();
    for (int d = 1; d < 256; d <<= 1) {
        int t = (tid >= d) ? ssum[tid - d] : 0;
        __syncthreads();
        ssum[tid] += t;
        __syncthreads();
    }
    int pref = ssum[tid] - (h0 + h1);
    if (2 * tid < NBK) excl[2 * tid] = pref;
    if (2 * tid + 1 < NBK) excl[2 * tid + 1] = pref + h0;
    for (int b = tid; b < NBK; b += 256) {
        int c = hist[b];
        runbase[b] = c ? atomicAdd(&gcur[b], c) : 0;
    }
    __syncthreads();
    #pragma unroll
    for (int k = 0; k < CHUNK / 256; k++) {
        if (bk[k] >= 0) {
            int r = atomicAdd(&excl[bk[k]], 1);
            sorted[r] = ed[k];
        }
    }
    __syncthreads();
    for (int i = tid; i < n; i += 256) {
        int2 e = sorted[i];
        int b = e.y >> BKS;
        int local_rank = i - (excl[b] - hist[b]);
        ebuf[runbase[b] + local_rank] = e;
    }
}

__global__ __launch_bounds__(256) void bucket_csr(const int2* __restrict__ ebuf, const int* __restrict__ gbase,
                                                  const int* __restrict__ gcnt,
                                                  int* __restrict__ offs, int* __restrict__ csr) {
    __shared__ int hist[256], cur[256], ssum[256];
    int b = blockIdx.x, tid = threadIdx.x;
    int ebeg = gbase[b], cnt = gcnt[b];
    int node0 = b << BKS;
    hist[tid] = 0;
    __syncthreads();
    for (int i = ebeg + tid; i < ebeg + cnt; i += 256)
        atomicAdd(&hist[ebuf[i].y & 255], 1);
    __syncthreads();
    int v = hist[tid];
    ssum[tid] = v;
    __syncthreads();
    for (int d = 1; d < 256; d <<= 1) {
        int t = (tid >= d) ? ssum[tid - d] : 0;
        __syncthreads();
        ssum[tid] += t;
        __syncthreads();
    }
    int ex = ebeg + ssum[tid] - v;
    cur[tid] = ex;
    int nnode = NN - node0; if (nnode > 256) nnode = 256;
    if (tid < nnode) offs[node0 + tid] = ex;
    if (b == NBK - 1 && tid == nnode - 1) offs[NN] = ebeg + cnt;
    __syncthreads();
    for (int i = ebeg + tid; i < ebeg + cnt; i += 256) {
        int2 e = ebuf[i];
        int pos = atomicAdd(&cur[e.y & 255], 1);
        csr[pos] = e.x;
    }
}

// ---------------- split-bf16 MFMA GEMM, pipelined (T14) + fragment-native LDS ----------------
// h = x @ W via 3-term bf16 split (xh*wh + xh*wl + xl*wh); 16x16x32 bf16 MFMA.
// LDS holds FRAGMENTS: A[buf][kg][row][8], B[buf][kg][col][8] (hi+lo each).
// Frag reads: unit-stride 16B per lane (uniform banks). A-staging: 8B uint2 writes.
// B-staging: each thread owns a k-run of one col -> single aligned b64/b128 write.
// Pipeline per chunk: issue loads(t+1) -> MFMA(buf cur) -> convert+write(buf cur^1)
// (vmcnt wait lands here, after compute) -> ONE barrier.

template <int CIN, int COUT>
__global__ __launch_bounds__(256) void mfma_gemm(const float* __restrict__ in, const float* __restrict__ W,
                                                 const float* __restrict__ a_s, const float* __restrict__ a_d,
                                                 float* __restrict__ h, float* __restrict__ asv,
                                                 float* __restrict__ adv) {
    const int KC  = 32;
    const int BM  = 128;
    const int NCT = COUT / 16;       // col tiles: 4 (COUT=64) or 2 (COUT=32)
    const int NCH = CIN / KC;
    const int TPC = 256 / COUT;      // threads per col-slot group: 4 or 8
    const int KPER = KC / TPC;       // k's per thread for W staging: 8 or 4

    __shared__ unsigned short Ah[2][4 * BM * 8];     // 16 KB
    __shared__ unsigned short Al[2][4 * BM * 8];     // 16 KB
    __shared__ unsigned short Bh[2][4 * COUT * 8];   // 8 / 4 KB
    __shared__ unsigned short Bl[2][4 * COUT * 8];

    int tid  = threadIdx.x;
    int lane = tid & 63;
    int wave = tid >> 6;
    int fr = lane & 15;              // free-dim index within 16-tile
    int kg = lane >> 4;              // k-group (0..3), 8 k each
    int n0base = blockIdx.x * BM;

    int wcol = tid % COUT;
    int kseg = tid / COUT;
    int kb   = kseg * KPER;
    int kgW  = kb >> 3;
    int kofW = kb & 7;

    float4 xr[4];
    float  wreg[KPER];

    f32x4 acc[2][NCT];
    #pragma unroll
    for (int rt = 0; rt < 2; rt++)
        #pragma unroll
        for (int ct = 0; ct < NCT; ct++) acc[rt][ct] = (f32x4){0.f, 0.f, 0.f, 0.f};

    auto load_regs = [&](int k0) {
        #pragma unroll
        for (int i = 0; i < 4; i++) {
            int f = tid + i * 256;
            int row = f >> 3, q = f & 7;
            int gn = n0base + row;
            xr[i] = make_float4(0.f, 0.f, 0.f, 0.f);
            if (gn < NN) xr[i] = *(const float4*)&in[(size_t)gn * CIN + k0 + q * 4];
        }
        #pragma unroll
        for (int j = 0; j < KPER; j++)
            wreg[j] = W[(size_t)(k0 + kb + j) * COUT + wcol];
    };

    auto write_lds = [&](int buf) {
        #pragma unroll
        for (int i = 0; i < 4; i++) {
            int f = tid + i * 256;
            int row = f >> 3, q = f & 7;
            int akg = q >> 1, off = (q & 1) * 4;
            uint2 hi, lo;
            split4(xr[i], hi, lo);
            *(uint2*)&Ah[buf][(akg * BM + row) * 8 + off] = hi;
            *(uint2*)&Al[buf][(akg * BM + row) * 8 + off] = lo;
        }
        unsigned short bh8[8], bl8[8];
        #pragma unroll
        for (int j = 0; j < KPER; j++) {
            bh8[j] = f2bf(wreg[j]);
            bl8[j] = f2bf(wreg[j] - bf2f(bh8[j]));
        }
        if constexpr (KPER == 8) {
            uint4 ph = make_uint4((unsigned)bh8[0] | ((unsigned)bh8[1] << 16), (unsigned)bh8[2] | ((unsigned)bh8[3] << 16),
                                  (unsigned)bh8[4] | ((unsigned)bh8[5] << 16), (unsigned)bh8[6] | ((unsigned)bh8[7] << 16));
            uint4 pl = make_uint4((unsigned)bl8[0] | ((unsigned)bl8[1] << 16), (unsigned)bl8[2] | ((unsigned)bl8[3] << 16),
                                  (unsigned)bl8[4] | ((unsigned)bl8[5] << 16), (unsigned)bl8[6] | ((unsigned)bl8[7] << 16));
            *(uint4*)&Bh[buf][(kgW * COUT + wcol) * 8 + kofW] = ph;
            *(uint4*)&Bl[buf][(kgW * COUT + wcol) * 8 + kofW] = pl;
        } else {
            uint2 ph = make_uint2((unsigned)bh8[0] | ((unsigned)bh8[1] << 16), (unsigned)bh8[2] | ((unsigned)bh8[3] << 16));
            uint2 pl = make_uint2((unsigned)bl8[0] | ((unsigned)bl8[1] << 16), (unsigned)bl8[2] | ((unsigned)bl8[3] << 16));
            *(uint2*)&Bh[buf][(kgW * COUT + wcol) * 8 + kofW] = ph;
            *(uint2*)&Bl[buf][(kgW * COUT + wcol) * 8 + kofW] = pl;
        }
    };

    auto do_mfma = [&](int buf) {
        bf16x8 ah[2], al[2];
        #pragma unroll
        for (int rt = 0; rt < 2; rt++) {
            int row = wave * 32 + rt * 16 + fr;
            ah[rt] = *(const bf16x8*)&Ah[buf][(kg * BM + row) * 8];
            al[rt] = *(const bf16x8*)&Al[buf][(kg * BM + row) * 8];
        }
        #pragma unroll
        for (int ct = 0; ct < NCT; ct++) {
            int col = ct * 16 + fr;
            bf16x8 bh = *(const bf16x8*)&Bh[buf][(kg * COUT + col) * 8];
            bf16x8 bl = *(const bf16x8*)&Bl[buf][(kg * COUT + col) * 8];
            #pragma unroll
            for (int rt = 0; rt < 2; rt++) {
                acc[rt][ct] = __builtin_amdgcn_mfma_f32_16x16x32_bf16(ah[rt], bh, acc[rt][ct], 0, 0, 0);
                acc[rt][ct] = __builtin_amdgcn_mfma_f32_16x16x32_bf16(ah[rt], bl, acc[rt][ct], 0, 0, 0);
                acc[rt][ct] = __builtin_amdgcn_mfma_f32_16x16x32_bf16(al[rt], bh, acc[rt][ct], 0, 0, 0);
            }
        }
    };

    // prologue: stage chunk 0
    load_regs(0);
    write_lds(0);
    __syncthreads();

    for (int t = 0; t < NCH; t++) {
        int cur = t & 1;
        if (t + 1 < NCH) load_regs((t + 1) * KC);   // in flight during MFMA
        do_mfma(cur);
        if (t + 1 < NCH) {
            write_lds(cur ^ 1);                     // vmcnt wait lands here, post-compute
            __syncthreads();
        }
    }

    // ---- epilogue: h store + fused a_s/a_d dots (16-lane shfl reduce) ----
    float As_l[NCT], Ad_l[NCT];
    #pragma unroll
    for (int ct = 0; ct < NCT; ct++) {
        As_l[ct] = a_s[ct * 16 + fr];
        Ad_l[ct] = a_d[ct * 16 + fr];
    }
    #pragma unroll
    for (int rt = 0; rt < 2; rt++) {
        #pragma unroll
        for (int r = 0; r < 4; r++) {
            int row = n0base + wave * 32 + rt * 16 + kg * 4 + r;
            if (row < NN) {
                #pragma unroll
                for (int ct = 0; ct < NCT; ct++)
                    h[(size_t)row * COUT + ct * 16 + fr] = acc[rt][ct][r];
            }
            float ps = 0.f, pd = 0.f;
            #pragma unroll
            for (int ct = 0; ct < NCT; ct++) {
                ps += acc[rt][ct][r] * As_l[ct];
                pd += acc[rt][ct][r] * Ad_l[ct];
            }
            #pragma unroll
            for (int off = 1; off < 16; off <<= 1) {
                ps += __shfl_xor(ps, off);
                pd += __shfl_xor(pd, off);
            }
            if (fr == 0 && row < NN) { asv[row] = ps; adv[row] = pd; }
        }
    }
}

// ---------------- fused aggregate (unchanged) ----------------

template <int C, bool ACT>
__global__ __launch_bounds__(256) void gat_agg(const float* __restrict__ h, const float* __restrict__ asv,
                                               const float* __restrict__ adv, const int* __restrict__ offs,
                                               const int* __restrict__ csr,
                                               const float* __restrict__ bias, float* __restrict__ out) {
    const int LPR = C / 4;
    const int G = 64 / LPR;
    const float4* h4 = (const float4*)h;
    int lane = threadIdx.x & 63;
    int v = blockIdx.x * 4 + (threadIdx.x >> 6);
    int beg = offs[v], end = offs[v + 1];
    int g = lane / LPR, r = lane % LPR;
    float adv_v = adv[v];

    float4 acc = {0.f, 0.f, 0.f, 0.f};
    float dsum = 0.f;
    #pragma unroll 4
    for (int e = beg + g; e < end; e += G) {
        int s = csr[e];
        float ww = __expf(lrelu02(asv[s] + adv_v));
        float4 hv = h4[(size_t)s * LPR + r];
        dsum += ww;
        acc.x += ww * hv.x; acc.y += ww * hv.y; acc.z += ww * hv.z; acc.w += ww * hv.w;
    }
    #pragma unroll
    for (int off = LPR; off < 64; off <<= 1) {
        acc.x += __shfl_xor(acc.x, off);
        acc.y += __shfl_xor(acc.y, off);
        acc.z += __shfl_xor(acc.z, off);
        acc.w += __shfl_xor(acc.w, off);
        dsum += __shfl_xor(dsum, off);
    }
    if (g == 0) {
        float selfw = __expf(lrelu02(asv[v] + adv_v));
        float4 hs = h4[(size_t)v * LPR + r];
        acc.x += selfw * hs.x; acc.y += selfw * hs.y;
        acc.z += selfw * hs.z; acc.w += selfw * hs.w;
        dsum += selfw;
        float inv = 1.f / (dsum + 1e-16f);
        float4 bb = ((const float4*)bias)[r];
        float4 o;
        o.x = acc.x * inv + bb.x; o.y = acc.y * inv + bb.y;
        o.z = acc.z * inv + bb.z; o.w = acc.w * inv + bb.w;
        if (ACT) {
            o.x = fmaxf(o.x, 0.01f * o.x); o.y = fmaxf(o.y, 0.01f * o.y);
            o.z = fmaxf(o.z, 0.01f * o.z); o.w = fmaxf(o.w, 0.01f * o.w);
        }
        ((float4*)out)[(size_t)v * LPR + r] = o;
    }
}

// ---------------- launch ----------------

extern "C" void kernel_launch(void* const* d_in, const int* in_sizes, int n_in,
                              void* d_out, int out_size, void* d_ws, size_t ws_size,
                              hipStream_t stream) {
    const float* x   = (const float*)d_in[0];
    const int*   ei  = (const int*)d_in[1];
    const float* W1  = (const float*)d_in[2];
    const float* as1 = (const float*)d_in[3];
    const float* ad1 = (const float*)d_in[4];
    const float* b1  = (const float*)d_in[5];
    const float* W2  = (const float*)d_in[6];
    const float* as2 = (const float*)d_in[7];
    const float* ad2 = (const float*)d_in[8];
    const float* b2  = (const float*)d_in[9];
    const float* W3  = (const float*)d_in[10];
    const float* as3 = (const float*)d_in[11];
    const float* ad3 = (const float*)d_in[12];
    const float* b3  = (const float*)d_in[13];
    float* out = (float*)d_out;

    const int* srcp = ei;
    const int* dstp = ei + NE;

    char* w = (char*)d_ws;
    float* h     = (float*)w;   w += sizeof(float) * (size_t)NN * HD;
    float* featB = (float*)w;   w += sizeof(float) * (size_t)NN * HD;
    float* asv   = (float*)w;   w += sizeof(float) * NN;
    float* advv  = (float*)w;   w += sizeof(float) * NN;
    int* offs    = (int*)w;     w += sizeof(int) * (NN + 1);
    int* csr     = (int*)w;     w += sizeof(int) * (size_t)NE;
    int2* ebuf   = (int2*)w;    w += sizeof(int2) * (size_t)NE;
    int* gcnt    = (int*)w;     w += sizeof(int) * NBK;
    int* gbase   = (int*)w;     w += sizeof(int) * NBK;
    int* gcur    = (int*)w;     w += sizeof(int) * NBK;

    const int GBM = (NN + 127) / 128;   // 782 blocks

    // CSR build (bucketed counting sort; shared across all 3 layers)
    hipMemsetAsync(gcnt, 0, sizeof(int) * NBK, stream);
    bucket_hist<<<NBLK, 256, 0, stream>>>(dstp, gcnt);
    bucket_scan<<<1, 512, 0, stream>>>(gcnt, gbase, gcur);
    bin_edges<<<NBLK, 256, 0, stream>>>(srcp, dstp, gcur, ebuf);
    bucket_csr<<<NBK, 256, 0, stream>>>(ebuf, gbase, gcnt, offs, csr);

    // layer 1
    mfma_gemm<NF, HD><<<GBM, 256, 0, stream>>>(x, W1, as1, ad1, h, asv, advv);
    gat_agg<HD, true><<<NN / 4, 256, 0, stream>>>(h, asv, advv, offs, csr, b1, featB);

    // layer 2
    mfma_gemm<HD, HD><<<GBM, 256, 0, stream>>>(featB, W2, as2, ad2, h, asv, advv);
    gat_agg<HD, true><<<NN / 4, 256, 0, stream>>>(h, asv, advv, offs, csr, b2, featB);

    // layer 3
    mfma_gemm<HD, NC><<<GBM, 256, 0, stream>>>(featB, W3, as3, ad3, h, asv, advv);
    gat_agg<NC, false><<<NN / 4, 256, 0, stream>>>(h, asv, advv, offs, csr, b3, out);
}

// Round 7
// 434.295 us; speedup vs baseline: 1.1597x; 1.0466x over previous
//
#include <hip/hip_runtime.h>

#define NN 100000
#define NE 1600000
#define NF 256
#define HD 64
#define NC 32

#define BKS 8
#define NBK ((NN + 255) >> 8)      // 391 buckets of 256 nodes
#define CHUNK 4096                 // edges per bin_edges block
#define NBLK ((NE + CHUNK - 1) / CHUNK)  // 391

__device__ __forceinline__ float lrelu02(float x) { return fmaxf(x, 0.2f * x); }

typedef __attribute__((ext_vector_type(8))) short bf16x8;
typedef __attribute__((ext_vector_type(4))) float f32x4;
typedef __attribute__((ext_vector_type(4))) _Float16 f16x4;

// round-to-nearest-even f32 -> bf16 (finite inputs)
__device__ __forceinline__ unsigned short f2bf(float f) {
    unsigned int u = __float_as_uint(f);
    unsigned int r = u + 0x7FFFu + ((u >> 16) & 1u);
    return (unsigned short)(r >> 16);
}
__device__ __forceinline__ float bf2f(unsigned short s) {
    return __uint_as_float(((unsigned int)s) << 16);
}
__device__ __forceinline__ void split4(float4 v, uint2& hi, uint2& lo) {
    unsigned short h0 = f2bf(v.x), h1 = f2bf(v.y), h2 = f2bf(v.z), h3 = f2bf(v.w);
    unsigned short l0 = f2bf(v.x - bf2f(h0)), l1 = f2bf(v.y - bf2f(h1));
    unsigned short l2 = f2bf(v.z - bf2f(h2)), l3 = f2bf(v.w - bf2f(h3));
    hi.x = (unsigned int)h0 | ((unsigned int)h1 << 16);
    hi.y = (unsigned int)h2 | ((unsigned int)h3 << 16);
    lo.x = (unsigned int)l0 | ((unsigned int)l1 << 16);
    lo.y = (unsigned int)l2 | ((unsigned int)l3 << 16);
}

// ---------------- CSR build via bucketed counting sort (unchanged) ----------------

__global__ __launch_bounds__(256) void bucket_hist(const int* __restrict__ dst, int* __restrict__ gcnt) {
    __shared__ int hist[NBK];
    int tid = threadIdx.x;
    for (int i = tid; i < NBK; i += 256) hist[i] = 0;
    __syncthreads();
    int base = blockIdx.x * CHUNK;
    #pragma unroll
    for (int k = 0; k < CHUNK / 256; k++) {
        int i = base + k * 256 + tid;
        if (i < NE) atomicAdd(&hist[dst[i] >> BKS], 1);
    }
    __syncthreads();
    for (int i = tid; i < NBK; i += 256) if (hist[i]) atomicAdd(&gcnt[i], hist[i]);
}

__global__ void bucket_scan(const int* __restrict__ gcnt, int* __restrict__ gbase, int* __restrict__ gcur) {
    __shared__ int sh[512];
    int tid = threadIdx.x;
    int v = (tid < NBK) ? gcnt[tid] : 0;
    sh[tid] = v;
    __syncthreads();
    for (int d = 1; d < 512; d <<= 1) {
        int t = (tid >= d) ? sh[tid - d] : 0;
        __syncthreads();
        sh[tid] += t;
        __syncthreads();
    }
    if (tid < NBK) { int ex = sh[tid] - v; gbase[tid] = ex; gcur[tid] = ex; }
}

__global__ __launch_bounds__(256) void bin_edges(const int* __restrict__ src, const int* __restrict__ dst,
                                                 int* __restrict__ gcur, int2* __restrict__ ebuf) {
    __shared__ int hist[NBK];
    __shared__ int excl[NBK];
    __shared__ int runbase[NBK];
    __shared__ int ssum[256];
    __shared__ int2 sorted[CHUNK];   // 32 KB
    int tid = threadIdx.x;
    int base = blockIdx.x * CHUNK;
    int n = NE - base; if (n > CHUNK) n = CHUNK;

    for (int i = tid; i < NBK; i += 256) hist[i] = 0;
    __syncthreads();

    int2 ed[CHUNK / 256];
    int bk[CHUNK / 256];
    #pragma unroll
    for (int k = 0; k < CHUNK / 256; k++) {
        int i = base + k * 256 + tid;
        if (i < NE) {
            ed[k] = make_int2(src[i], dst[i]);
            bk[k] = ed[k].y >> BKS;
            atomicAdd(&hist[bk[k]], 1);
        } else bk[k] = -1;
    }
    __syncthreads();
    int h0 = (2 * tid < NBK) ? hist[2 * tid] : 0;
    int h1 = (2 * tid + 1 < NBK) ? hist[2 * tid + 1] : 0;
    ssum[tid] = h0 + h1;
    __syncthreads();
    for (int d = 1; d < 256; d <<= 1) {
        int t = (tid >= d) ? ssum[tid - d] : 0;
        __syncthreads();
        ssum[tid] += t;
        __syncthreads();
    }
    int pref = ssum[tid] - (h0 + h1);
    if (2 * tid < NBK) excl[2 * tid] = pref;
    if (2 * tid + 1 < NBK) excl[2 * tid + 1] = pref + h0;
    for (int b = tid; b < NBK; b += 256) {
        int c = hist[b];
        runbase[b] = c ? atomicAdd(&gcur[b], c) : 0;
    }
    __syncthreads();
    #pragma unroll
    for (int k = 0; k < CHUNK / 256; k++) {
        if (bk[k] >= 0) {
            int r = atomicAdd(&excl[bk[k]], 1);
            sorted[r] = ed[k];
        }
    }
    __syncthreads();
    for (int i = tid; i < n; i += 256) {
        int2 e = sorted[i];
        int b = e.y >> BKS;
        int local_rank = i - (excl[b] - hist[b]);
        ebuf[runbase[b] + local_rank] = e;
    }
}

__global__ __launch_bounds__(256) void bucket_csr(const int2* __restrict__ ebuf, const int* __restrict__ gbase,
                                                  const int* __restrict__ gcnt,
                                                  int* __restrict__ offs, int* __restrict__ csr) {
    __shared__ int hist[256], cur[256], ssum[256];
    int b = blockIdx.x, tid = threadIdx.x;
    int ebeg = gbase[b], cnt = gcnt[b];
    int node0 = b << BKS;
    hist[tid] = 0;
    __syncthreads();
    for (int i = ebeg + tid; i < ebeg + cnt; i += 256)
        atomicAdd(&hist[ebuf[i].y & 255], 1);
    __syncthreads();
    int v = hist[tid];
    ssum[tid] = v;
    __syncthreads();
    for (int d = 1; d < 256; d <<= 1) {
        int t = (tid >= d) ? ssum[tid - d] : 0;
        __syncthreads();
        ssum[tid] += t;
        __syncthreads();
    }
    int ex = ebeg + ssum[tid] - v;
    cur[tid] = ex;
    int nnode = NN - node0; if (nnode > 256) nnode = 256;
    if (tid < nnode) offs[node0 + tid] = ex;
    if (b == NBK - 1 && tid == nnode - 1) offs[NN] = ebeg + cnt;
    __syncthreads();
    for (int i = ebeg + tid; i < ebeg + cnt; i += 256) {
        int2 e = ebuf[i];
        int pos = atomicAdd(&cur[e.y & 255], 1);
        csr[pos] = e.x;
    }
}

// ---------------- split-bf16 MFMA GEMM, pipelined, fp16 h output ----------------
// h = x @ W via 3-term bf16 split (xh*wh + xh*wl + xl*wh); 16x16x32 bf16 MFMA.
// h is written ONLY as fp16 (the aggregation's message plane): halves both the
// GEMM write traffic and the downstream gather traffic. asv/adv computed in f32.

template <int CIN, int COUT>
__global__ __launch_bounds__(256) void mfma_gemm(const float* __restrict__ in, const float* __restrict__ W,
                                                 const float* __restrict__ a_s, const float* __restrict__ a_d,
                                                 _Float16* __restrict__ hout, float* __restrict__ asv,
                                                 float* __restrict__ adv) {
    const int KC  = 32;
    const int BM  = 128;
    const int NCT = COUT / 16;       // col tiles: 4 (COUT=64) or 2 (COUT=32)
    const int NCH = CIN / KC;
    const int TPC = 256 / COUT;      // threads per col-slot group: 4 or 8
    const int KPER = KC / TPC;       // k's per thread for W staging: 8 or 4

    __shared__ unsigned short Ah[2][4 * BM * 8];     // 16 KB
    __shared__ unsigned short Al[2][4 * BM * 8];     // 16 KB
    __shared__ unsigned short Bh[2][4 * COUT * 8];   // 8 / 4 KB
    __shared__ unsigned short Bl[2][4 * COUT * 8];

    int tid  = threadIdx.x;
    int lane = tid & 63;
    int wave = tid >> 6;
    int fr = lane & 15;              // free-dim index within 16-tile
    int kg = lane >> 4;              // k-group (0..3), 8 k each
    int n0base = blockIdx.x * BM;

    int wcol = tid % COUT;
    int kseg = tid / COUT;
    int kb   = kseg * KPER;
    int kgW  = kb >> 3;
    int kofW = kb & 7;

    float4 xr[4];
    float  wreg[KPER];

    f32x4 acc[2][NCT];
    #pragma unroll
    for (int rt = 0; rt < 2; rt++)
        #pragma unroll
        for (int ct = 0; ct < NCT; ct++) acc[rt][ct] = (f32x4){0.f, 0.f, 0.f, 0.f};

    auto load_regs = [&](int k0) {
        #pragma unroll
        for (int i = 0; i < 4; i++) {
            int f = tid + i * 256;
            int row = f >> 3, q = f & 7;
            int gn = n0base + row;
            xr[i] = make_float4(0.f, 0.f, 0.f, 0.f);
            if (gn < NN) xr[i] = *(const float4*)&in[(size_t)gn * CIN + k0 + q * 4];
        }
        #pragma unroll
        for (int j = 0; j < KPER; j++)
            wreg[j] = W[(size_t)(k0 + kb + j) * COUT + wcol];
    };

    auto write_lds = [&](int buf) {
        #pragma unroll
        for (int i = 0; i < 4; i++) {
            int f = tid + i * 256;
            int row = f >> 3, q = f & 7;
            int akg = q >> 1, off = (q & 1) * 4;
            uint2 hi, lo;
            split4(xr[i], hi, lo);
            *(uint2*)&Ah[buf][(akg * BM + row) * 8 + off] = hi;
            *(uint2*)&Al[buf][(akg * BM + row) * 8 + off] = lo;
        }
        unsigned short bh8[8], bl8[8];
        #pragma unroll
        for (int j = 0; j < KPER; j++) {
            bh8[j] = f2bf(wreg[j]);
            bl8[j] = f2bf(wreg[j] - bf2f(bh8[j]));
        }
        if constexpr (KPER == 8) {
            uint4 ph = make_uint4((unsigned)bh8[0] | ((unsigned)bh8[1] << 16), (unsigned)bh8[2] | ((unsigned)bh8[3] << 16),
                                  (unsigned)bh8[4] | ((unsigned)bh8[5] << 16), (unsigned)bh8[6] | ((unsigned)bh8[7] << 16));
            uint4 pl = make_uint4((unsigned)bl8[0] | ((unsigned)bl8[1] << 16), (unsigned)bl8[2] | ((unsigned)bl8[3] << 16),
                                  (unsigned)bl8[4] | ((unsigned)bl8[5] << 16), (unsigned)bl8[6] | ((unsigned)bl8[7] << 16));
            *(uint4*)&Bh[buf][(kgW * COUT + wcol) * 8 + kofW] = ph;
            *(uint4*)&Bl[buf][(kgW * COUT + wcol) * 8 + kofW] = pl;
        } else {
            uint2 ph = make_uint2((unsigned)bh8[0] | ((unsigned)bh8[1] << 16), (unsigned)bh8[2] | ((unsigned)bh8[3] << 16));
            uint2 pl = make_uint2((unsigned)bl8[0] | ((unsigned)bl8[1] << 16), (unsigned)bl8[2] | ((unsigned)bl8[3] << 16));
            *(uint2*)&Bh[buf][(kgW * COUT + wcol) * 8 + kofW] = ph;
            *(uint2*)&Bl[buf][(kgW * COUT + wcol) * 8 + kofW] = pl;
        }
    };

    auto do_mfma = [&](int buf) {
        bf16x8 ah[2], al[2];
        #pragma unroll
        for (int rt = 0; rt < 2; rt++) {
            int row = wave * 32 + rt * 16 + fr;
            ah[rt] = *(const bf16x8*)&Ah[buf][(kg * BM + row) * 8];
            al[rt] = *(const bf16x8*)&Al[buf][(kg * BM + row) * 8];
        }
        #pragma unroll
        for (int ct = 0; ct < NCT; ct++) {
            int col = ct * 16 + fr;
            bf16x8 bh = *(const bf16x8*)&Bh[buf][(kg * COUT + col) * 8];
            bf16x8 bl = *(const bf16x8*)&Bl[buf][(kg * COUT + col) * 8];
            #pragma unroll
            for (int rt = 0; rt < 2; rt++) {
                acc[rt][ct] = __builtin_amdgcn_mfma_f32_16x16x32_bf16(ah[rt], bh, acc[rt][ct], 0, 0, 0);
                acc[rt][ct] = __builtin_amdgcn_mfma_f32_16x16x32_bf16(ah[rt], bl, acc[rt][ct], 0, 0, 0);
                acc[rt][ct] = __builtin_amdgcn_mfma_f32_16x16x32_bf16(al[rt], bh, acc[rt][ct], 0, 0, 0);
            }
        }
    };

    // prologue: stage chunk 0
    load_regs(0);
    write_lds(0);
    __syncthreads();

    for (int t = 0; t < NCH; t++) {
        int cur = t & 1;
        if (t + 1 < NCH) load_regs((t + 1) * KC);   // in flight during MFMA
        do_mfma(cur);
        if (t + 1 < NCH) {
            write_lds(cur ^ 1);                     // vmcnt wait lands here, post-compute
            __syncthreads();
        }
    }

    // ---- epilogue: fp16 h store + fused a_s/a_d dots (16-lane shfl reduce) ----
    float As_l[NCT], Ad_l[NCT];
    #pragma unroll
    for (int ct = 0; ct < NCT; ct++) {
        As_l[ct] = a_s[ct * 16 + fr];
        Ad_l[ct] = a_d[ct * 16 + fr];
    }
    #pragma unroll
    for (int rt = 0; rt < 2; rt++) {
        #pragma unroll
        for (int r = 0; r < 4; r++) {
            int row = n0base + wave * 32 + rt * 16 + kg * 4 + r;
            if (row < NN) {
                #pragma unroll
                for (int ct = 0; ct < NCT; ct++)
                    hout[(size_t)row * COUT + ct * 16 + fr] = (_Float16)acc[rt][ct][r];
            }
            float ps = 0.f, pd = 0.f;
            #pragma unroll
            for (int ct = 0; ct < NCT; ct++) {
                ps += acc[rt][ct][r] * As_l[ct];
                pd += acc[rt][ct][r] * Ad_l[ct];
            }
            #pragma unroll
            for (int off = 1; off < 16; off <<= 1) {
                ps += __shfl_xor(ps, off);
                pd += __shfl_xor(pd, off);
            }
            if (fr == 0 && row < NN) { asv[row] = ps; adv[row] = pd; }
        }
    }
}

// ---------------- fused aggregate: fp16 message gather ----------------

template <int C, bool ACT>
__global__ __launch_bounds__(256) void gat_agg(const _Float16* __restrict__ h16, const float* __restrict__ asv,
                                               const float* __restrict__ adv, const int* __restrict__ offs,
                                               const int* __restrict__ csr,
                                               const float* __restrict__ bias, float* __restrict__ out) {
    const int LPR = C / 4;
    const int G = 64 / LPR;
    const f16x4* hh = (const f16x4*)h16;
    int lane = threadIdx.x & 63;
    int v = blockIdx.x * 4 + (threadIdx.x >> 6);
    int beg = offs[v], end = offs[v + 1];
    int g = lane / LPR, r = lane % LPR;
    float adv_v = adv[v];

    float4 acc = {0.f, 0.f, 0.f, 0.f};
    float dsum = 0.f;
    #pragma unroll 4
    for (int e = beg + g; e < end; e += G) {
        int s = csr[e];
        float ww = __expf(lrelu02(asv[s] + adv_v));
        f16x4 hv = hh[(size_t)s * LPR + r];
        dsum += ww;
        acc.x += ww * (float)hv[0]; acc.y += ww * (float)hv[1];
        acc.z += ww * (float)hv[2]; acc.w += ww * (float)hv[3];
    }
    #pragma unroll
    for (int off = LPR; off < 64; off <<= 1) {
        acc.x += __shfl_xor(acc.x, off);
        acc.y += __shfl_xor(acc.y, off);
        acc.z += __shfl_xor(acc.z, off);
        acc.w += __shfl_xor(acc.w, off);
        dsum += __shfl_xor(dsum, off);
    }
    if (g == 0) {
        float selfw = __expf(lrelu02(asv[v] + adv_v));
        f16x4 hs = hh[(size_t)v * LPR + r];
        acc.x += selfw * (float)hs[0]; acc.y += selfw * (float)hs[1];
        acc.z += selfw * (float)hs[2]; acc.w += selfw * (float)hs[3];
        dsum += selfw;
        float inv = 1.f / (dsum + 1e-16f);
        float4 bb = ((const float4*)bias)[r];
        float4 o;
        o.x = acc.x * inv + bb.x; o.y = acc.y * inv + bb.y;
        o.z = acc.z * inv + bb.z; o.w = acc.w * inv + bb.w;
        if (ACT) {
            o.x = fmaxf(o.x, 0.01f * o.x); o.y = fmaxf(o.y, 0.01f * o.y);
            o.z = fmaxf(o.z, 0.01f * o.z); o.w = fmaxf(o.w, 0.01f * o.w);
        }
        ((float4*)out)[(size_t)v * LPR + r] = o;
    }
}

// ---------------- launch ----------------

extern "C" void kernel_launch(void* const* d_in, const int* in_sizes, int n_in,
                              void* d_out, int out_size, void* d_ws, size_t ws_size,
                              hipStream_t stream) {
    const float* x   = (const float*)d_in[0];
    const int*   ei  = (const int*)d_in[1];
    const float* W1  = (const float*)d_in[2];
    const float* as1 = (const float*)d_in[3];
    const float* ad1 = (const float*)d_in[4];
    const float* b1  = (const float*)d_in[5];
    const float* W2  = (const float*)d_in[6];
    const float* as2 = (const float*)d_in[7];
    const float* ad2 = (const float*)d_in[8];
    const float* b2  = (const float*)d_in[9];
    const float* W3  = (const float*)d_in[10];
    const float* as3 = (const float*)d_in[11];
    const float* ad3 = (const float*)d_in[12];
    const float* b3  = (const float*)d_in[13];
    float* out = (float*)d_out;

    const int* srcp = ei;
    const int* dstp = ei + NE;

    char* w = (char*)d_ws;
    _Float16* h16 = (_Float16*)w;  w += sizeof(_Float16) * (size_t)NN * HD;
    float* featB = (float*)w;   w += sizeof(float) * (size_t)NN * HD;
    float* asv   = (float*)w;   w += sizeof(float) * NN;
    float* advv  = (float*)w;   w += sizeof(float) * NN;
    int* offs    = (int*)w;     w += sizeof(int) * (NN + 1);
    int* csr     = (int*)w;     w += sizeof(int) * (size_t)NE;
    int2* ebuf   = (int2*)w;    w += sizeof(int2) * (size_t)NE;
    int* gcnt    = (int*)w;     w += sizeof(int) * NBK;
    int* gbase   = (int*)w;     w += sizeof(int) * NBK;
    int* gcur    = (int*)w;     w += sizeof(int) * NBK;

    const int GBM = (NN + 127) / 128;   // 782 blocks

    // CSR build (bucketed counting sort; shared across all 3 layers)
    hipMemsetAsync(gcnt, 0, sizeof(int) * NBK, stream);
    bucket_hist<<<NBLK, 256, 0, stream>>>(dstp, gcnt);
    bucket_scan<<<1, 512, 0, stream>>>(gcnt, gbase, gcur);
    bin_edges<<<NBLK, 256, 0, stream>>>(srcp, dstp, gcur, ebuf);
    bucket_csr<<<NBK, 256, 0, stream>>>(ebuf, gbase, gcnt, offs, csr);

    // layer 1
    mfma_gemm<NF, HD><<<GBM, 256, 0, stream>>>(x, W1, as1, ad1, h16, asv, advv);
    gat_agg<HD, true><<<NN / 4, 256, 0, stream>>>(h16, asv, advv, offs, csr, b1, featB);

    // layer 2
    mfma_gemm<HD, HD><<<GBM, 256, 0, stream>>>(featB, W2, as2, ad2, h16, asv, advv);
    gat_agg<HD, true><<<NN / 4, 256, 0, stream>>>(h16, asv, advv, offs, csr, b2, featB);

    // layer 3
    mfma_gemm<HD, NC><<<GBM, 256, 0, stream>>>(featB, W3, as3, ad3, h16, asv, advv);
    gat_agg<NC, false><<<NN / 4, 256, 0, stream>>>(h16, asv, advv, offs, csr, b3, out);
}

// Round 8
// 427.590 us; speedup vs baseline: 1.1779x; 1.0157x over previous
//
#include <hip/hip_runtime.h>

#define NN 100000
#define NE 1600000
#define NF 256
#define HD 64
#define NC 32

#define BKS 8
#define NBK ((NN + 255) >> 8)      // 391 buckets of 256 nodes
#define CHUNK 4096                 // edges per bin_edges block
#define NBLK ((NE + CHUNK - 1) / CHUNK)  // 391

__device__ __forceinline__ float lrelu02(float x) { return fmaxf(x, 0.2f * x); }

typedef __attribute__((ext_vector_type(8))) short bf16x8;
typedef __attribute__((ext_vector_type(4))) float f32x4;
typedef __attribute__((ext_vector_type(4))) _Float16 f16x4;

// round-to-nearest-even f32 -> bf16 (finite inputs)
__device__ __forceinline__ unsigned short f2bf(float f) {
    unsigned int u = __float_as_uint(f);
    unsigned int r = u + 0x7FFFu + ((u >> 16) & 1u);
    return (unsigned short)(r >> 16);
}
__device__ __forceinline__ float bf2f(unsigned short s) {
    return __uint_as_float(((unsigned int)s) << 16);
}

// ---------------- CSR build via bucketed counting sort (unchanged) ----------------

__global__ __launch_bounds__(256) void bucket_hist(const int* __restrict__ dst, int* __restrict__ gcnt) {
    __shared__ int hist[NBK];
    int tid = threadIdx.x;
    for (int i = tid; i < NBK; i += 256) hist[i] = 0;
    __syncthreads();
    int base = blockIdx.x * CHUNK;
    #pragma unroll
    for (int k = 0; k < CHUNK / 256; k++) {
        int i = base + k * 256 + tid;
        if (i < NE) atomicAdd(&hist[dst[i] >> BKS], 1);
    }
    __syncthreads();
    for (int i = tid; i < NBK; i += 256) if (hist[i]) atomicAdd(&gcnt[i], hist[i]);
}

__global__ void bucket_scan(const int* __restrict__ gcnt, int* __restrict__ gbase, int* __restrict__ gcur) {
    __shared__ int sh[512];
    int tid = threadIdx.x;
    int v = (tid < NBK) ? gcnt[tid] : 0;
    sh[tid] = v;
    __syncthreads();
    for (int d = 1; d < 512; d <<= 1) {
        int t = (tid >= d) ? sh[tid - d] : 0;
        __syncthreads();
        sh[tid] += t;
        __syncthreads();
    }
    if (tid < NBK) { int ex = sh[tid] - v; gbase[tid] = ex; gcur[tid] = ex; }
}

__global__ __launch_bounds__(256) void bin_edges(const int* __restrict__ src, const int* __restrict__ dst,
                                                 int* __restrict__ gcur, int2* __restrict__ ebuf) {
    __shared__ int hist[NBK];
    __shared__ int excl[NBK];
    __shared__ int runbase[NBK];
    __shared__ int ssum[256];
    __shared__ int2 sorted[CHUNK];   // 32 KB
    int tid = threadIdx.x;
    int base = blockIdx.x * CHUNK;
    int n = NE - base; if (n > CHUNK) n = CHUNK;

    for (int i = tid; i < NBK; i += 256) hist[i] = 0;
    __syncthreads();

    int2 ed[CHUNK / 256];
    int bk[CHUNK / 256];
    #pragma unroll
    for (int k = 0; k < CHUNK / 256; k++) {
        int i = base + k * 256 + tid;
        if (i < NE) {
            ed[k] = make_int2(src[i], dst[i]);
            bk[k] = ed[k].y >> BKS;
            atomicAdd(&hist[bk[k]], 1);
        } else bk[k] = -1;
    }
    __syncthreads();
    int h0 = (2 * tid < NBK) ? hist[2 * tid] : 0;
    int h1 = (2 * tid + 1 < NBK) ? hist[2 * tid + 1] : 0;
    ssum[tid] = h0 + h1;
    __syncthreads();
    for (int d = 1; d < 256; d <<= 1) {
        int t = (tid >= d) ? ssum[tid - d] : 0;
        __syncthreads();
        ssum[tid] += t;
        __syncthreads();
    }
    int pref = ssum[tid] - (h0 + h1);
    if (2 * tid < NBK) excl[2 * tid] = pref;
    if (2 * tid + 1 < NBK) excl[2 * tid + 1] = pref + h0;
    for (int b = tid; b < NBK; b += 256) {
        int c = hist[b];
        runbase[b] = c ? atomicAdd(&gcur[b], c) : 0;
    }
    __syncthreads();
    #pragma unroll
    for (int k = 0; k < CHUNK / 256; k++) {
        if (bk[k] >= 0) {
            int r = atomicAdd(&excl[bk[k]], 1);
            sorted[r] = ed[k];
        }
    }
    __syncthreads();
    for (int i = tid; i < n; i += 256) {
        int2 e = sorted[i];
        int b = e.y >> BKS;
        int local_rank = i - (excl[b] - hist[b]);
        ebuf[runbase[b] + local_rank] = e;
    }
}

__global__ __launch_bounds__(256) void bucket_csr(const int2* __restrict__ ebuf, const int* __restrict__ gbase,
                                                  const int* __restrict__ gcnt,
                                                  int* __restrict__ offs, int* __restrict__ csr) {
    __shared__ int hist[256], cur[256], ssum[256];
    int b = blockIdx.x, tid = threadIdx.x;
    int ebeg = gbase[b], cnt = gcnt[b];
    int node0 = b << BKS;
    hist[tid] = 0;
    __syncthreads();
    for (int i = ebeg + tid; i < ebeg + cnt; i += 256)
        atomicAdd(&hist[ebuf[i].y & 255], 1);
    __syncthreads();
    int v = hist[tid];
    ssum[tid] = v;
    __syncthreads();
    for (int d = 1; d < 256; d <<= 1) {
        int t = (tid >= d) ? ssum[tid - d] : 0;
        __syncthreads();
        ssum[tid] += t;
        __syncthreads();
    }
    int ex = ebeg + ssum[tid] - v;
    cur[tid] = ex;
    int nnode = NN - node0; if (nnode > 256) nnode = 256;
    if (tid < nnode) offs[node0 + tid] = ex;
    if (b == NBK - 1 && tid == nnode - 1) offs[NN] = ebeg + cnt;
    __syncthreads();
    for (int i = ebeg + tid; i < ebeg + cnt; i += 256) {
        int2 e = ebuf[i];
        int pos = atomicAdd(&cur[e.y & 255], 1);
        csr[pos] = e.x;
    }
}

// ---------------- split-bf16 MFMA GEMM: A in registers, B in LDS, 2-wave blocks ----------------
// Each wave's A-fragments are rows only IT consumes (lane(fr,kg) owns row fr, k-slice kg),
// so A loads go straight global->reg->convert (no LDS round trip, bit-identical values).
// Only B (shared across waves) is LDS-staged, double-buffered. BM=64, 128 threads,
// LDS 16/8 KB -> ~10 blocks/CU by LDS; grid 1563 -> ~6 blocks/CU -> ~12 waves/CU
// active TLP to hide global-load latency (the R6 structure was stuck at 3 blocks/CU).

template <int CIN, int COUT>
__global__ __launch_bounds__(128) void mfma_gemm(const float* __restrict__ in, const float* __restrict__ W,
                                                 const float* __restrict__ a_s, const float* __restrict__ a_d,
                                                 _Float16* __restrict__ hout, float* __restrict__ asv,
                                                 float* __restrict__ adv) {
    const int KC  = 32;
    const int BM  = 64;
    const int NCT = COUT / 16;       // col tiles: 4 (COUT=64) or 2 (COUT=32)
    const int NCH = CIN / KC;
    const int SPT = (4 * COUT) / 128;  // (kg,col) slots per thread: 2 or 1

    __shared__ unsigned short Bh[2][4 * COUT * 8];   // 8 / 4 KB
    __shared__ unsigned short Bl[2][4 * COUT * 8];

    int tid  = threadIdx.x;
    int lane = tid & 63;
    int wave = tid >> 6;             // 0..1
    int fr = lane & 15;              // free-dim index within 16-tile
    int kg = lane >> 4;              // k-group (0..3), 8 k each
    int n0base = blockIdx.x * BM;
    int rbase  = n0base + wave * 32;

    // B staging slots: slot s = tid + i*128 -> col = s % COUT, kg_s = s / COUT
    int scol[SPT], skg[SPT];
    #pragma unroll
    for (int i = 0; i < SPT; i++) {
        int s = tid + i * 128;
        scol[i] = s % COUT;
        skg[i]  = s / COUT;
    }

    float4 xr[4];                    // A staging: rt{0,1} x two float4 (8 k each)
    float  wv[SPT][8];               // B staging
    bf16x8 ah[2], al[2];             // converted A fragments

    f32x4 acc[2][NCT];
    #pragma unroll
    for (int rt = 0; rt < 2; rt++)
        #pragma unroll
        for (int ct = 0; ct < NCT; ct++) acc[rt][ct] = (f32x4){0.f, 0.f, 0.f, 0.f};

    auto load_A = [&](int k0) {
        #pragma unroll
        for (int rt = 0; rt < 2; rt++) {
            int gr = rbase + rt * 16 + fr;
            if (gr < NN) {
                const float* p = &in[(size_t)gr * CIN + k0 + kg * 8];
                xr[rt * 2 + 0] = *(const float4*)p;
                xr[rt * 2 + 1] = *(const float4*)(p + 4);
            } else {
                xr[rt * 2 + 0] = make_float4(0.f, 0.f, 0.f, 0.f);
                xr[rt * 2 + 1] = make_float4(0.f, 0.f, 0.f, 0.f);
            }
        }
    };
    auto conv_A = [&]() {
        #pragma unroll
        for (int rt = 0; rt < 2; rt++) {
            const float* v = (const float*)&xr[rt * 2];
            unsigned short hs[8], ls[8];
            #pragma unroll
            for (int j = 0; j < 8; j++) {
                hs[j] = f2bf(v[j]);
                ls[j] = f2bf(v[j] - bf2f(hs[j]));
            }
            ah[rt] = *(bf16x8*)hs;
            al[rt] = *(bf16x8*)ls;
        }
    };
    auto load_B = [&](int k0) {
        #pragma unroll
        for (int i = 0; i < SPT; i++)
            #pragma unroll
            for (int j = 0; j < 8; j++)
                wv[i][j] = W[(size_t)(k0 + skg[i] * 8 + j) * COUT + scol[i]];
    };
    auto write_B = [&](int buf) {
        #pragma unroll
        for (int i = 0; i < SPT; i++) {
            unsigned short hs[8], ls[8];
            #pragma unroll
            for (int j = 0; j < 8; j++) {
                hs[j] = f2bf(wv[i][j]);
                ls[j] = f2bf(wv[i][j] - bf2f(hs[j]));
            }
            int idx = (skg[i] * COUT + scol[i]) * 8;
            *(uint4*)&Bh[buf][idx] = *(uint4*)hs;
            *(uint4*)&Bl[buf][idx] = *(uint4*)ls;
        }
    };
    auto do_mfma = [&](int buf) {
        #pragma unroll
        for (int ct = 0; ct < NCT; ct++) {
            int col = ct * 16 + fr;
            bf16x8 bh = *(const bf16x8*)&Bh[buf][(kg * COUT + col) * 8];
            bf16x8 bl = *(const bf16x8*)&Bl[buf][(kg * COUT + col) * 8];
            #pragma unroll
            for (int rt = 0; rt < 2; rt++) {
                acc[rt][ct] = __builtin_amdgcn_mfma_f32_16x16x32_bf16(ah[rt], bh, acc[rt][ct], 0, 0, 0);
                acc[rt][ct] = __builtin_amdgcn_mfma_f32_16x16x32_bf16(ah[rt], bl, acc[rt][ct], 0, 0, 0);
                acc[rt][ct] = __builtin_amdgcn_mfma_f32_16x16x32_bf16(al[rt], bh, acc[rt][ct], 0, 0, 0);
            }
        }
    };

    // prologue: stage chunk 0
    load_A(0);
    load_B(0);
    conv_A();
    write_B(0);
    __syncthreads();

    for (int t = 0; t < NCH; t++) {
        int cur = t & 1;
        if (t + 1 < NCH) {                 // issue next-chunk loads early (T14)
            load_A((t + 1) * KC);
            load_B((t + 1) * KC);
        }
        do_mfma(cur);                      // regs (A) + LDS buf cur (B)
        if (t + 1 < NCH) {
            write_B(cur ^ 1);              // vmcnt wait lands here, post-MFMA
            conv_A();
            __syncthreads();
        }
    }

    // ---- epilogue: fp16 h store + fused a_s/a_d dots (16-lane shfl reduce) ----
    float As_l[NCT], Ad_l[NCT];
    #pragma unroll
    for (int ct = 0; ct < NCT; ct++) {
        As_l[ct] = a_s[ct * 16 + fr];
        Ad_l[ct] = a_d[ct * 16 + fr];
    }
    #pragma unroll
    for (int rt = 0; rt < 2; rt++) {
        #pragma unroll
        for (int r = 0; r < 4; r++) {
            int row = rbase + rt * 16 + kg * 4 + r;
            if (row < NN) {
                #pragma unroll
                for (int ct = 0; ct < NCT; ct++)
                    hout[(size_t)row * COUT + ct * 16 + fr] = (_Float16)acc[rt][ct][r];
            }
            float ps = 0.f, pd = 0.f;
            #pragma unroll
            for (int ct = 0; ct < NCT; ct++) {
                ps += acc[rt][ct][r] * As_l[ct];
                pd += acc[rt][ct][r] * Ad_l[ct];
            }
            #pragma unroll
            for (int off = 1; off < 16; off <<= 1) {
                ps += __shfl_xor(ps, off);
                pd += __shfl_xor(pd, off);
            }
            if (fr == 0 && row < NN) { asv[row] = ps; adv[row] = pd; }
        }
    }
}

// ---------------- fused aggregate: fp16 message gather ----------------

template <int C, bool ACT>
__global__ __launch_bounds__(256) void gat_agg(const _Float16* __restrict__ h16, const float* __restrict__ asv,
                                               const float* __restrict__ adv, const int* __restrict__ offs,
                                               const int* __restrict__ csr,
                                               const float* __restrict__ bias, float* __restrict__ out) {
    const int LPR = C / 4;
    const int G = 64 / LPR;
    const f16x4* hh = (const f16x4*)h16;
    int lane = threadIdx.x & 63;
    int v = blockIdx.x * 4 + (threadIdx.x >> 6);
    int beg = offs[v], end = offs[v + 1];
    int g = lane / LPR, r = lane % LPR;
    float adv_v = adv[v];

    float4 acc = {0.f, 0.f, 0.f, 0.f};
    float dsum = 0.f;
    #pragma unroll 4
    for (int e = beg + g; e < end; e += G) {
        int s = csr[e];
        float ww = __expf(lrelu02(asv[s] + adv_v));
        f16x4 hv = hh[(size_t)s * LPR + r];
        dsum += ww;
        acc.x += ww * (float)hv[0]; acc.y += ww * (float)hv[1];
        acc.z += ww * (float)hv[2]; acc.w += ww * (float)hv[3];
    }
    #pragma unroll
    for (int off = LPR; off < 64; off <<= 1) {
        acc.x += __shfl_xor(acc.x, off);
        acc.y += __shfl_xor(acc.y, off);
        acc.z += __shfl_xor(acc.z, off);
        acc.w += __shfl_xor(acc.w, off);
        dsum += __shfl_xor(dsum, off);
    }
    if (g == 0) {
        float selfw = __expf(lrelu02(asv[v] + adv_v));
        f16x4 hs = hh[(size_t)v * LPR + r];
        acc.x += selfw * (float)hs[0]; acc.y += selfw * (float)hs[1];
        acc.z += selfw * (float)hs[2]; acc.w += selfw * (float)hs[3];
        dsum += selfw;
        float inv = 1.f / (dsum + 1e-16f);
        float4 bb = ((const float4*)bias)[r];
        float4 o;
        o.x = acc.x * inv + bb.x; o.y = acc.y * inv + bb.y;
        o.z = acc.z * inv + bb.z; o.w = acc.w * inv + bb.w;
        if (ACT) {
            o.x = fmaxf(o.x, 0.01f * o.x); o.y = fmaxf(o.y, 0.01f * o.y);
            o.z = fmaxf(o.z, 0.01f * o.z); o.w = fmaxf(o.w, 0.01f * o.w);
        }
        ((float4*)out)[(size_t)v * LPR + r] = o;
    }
}

// ---------------- launch ----------------

extern "C" void kernel_launch(void* const* d_in, const int* in_sizes, int n_in,
                              void* d_out, int out_size, void* d_ws, size_t ws_size,
                              hipStream_t stream) {
    const float* x   = (const float*)d_in[0];
    const int*   ei  = (const int*)d_in[1];
    const float* W1  = (const float*)d_in[2];
    const float* as1 = (const float*)d_in[3];
    const float* ad1 = (const float*)d_in[4];
    const float* b1  = (const float*)d_in[5];
    const float* W2  = (const float*)d_in[6];
    const float* as2 = (const float*)d_in[7];
    const float* ad2 = (const float*)d_in[8];
    const float* b2  = (const float*)d_in[9];
    const float* W3  = (const float*)d_in[10];
    const float* as3 = (const float*)d_in[11];
    const float* ad3 = (const float*)d_in[12];
    const float* b3  = (const float*)d_in[13];
    float* out = (float*)d_out;

    const int* srcp = ei;
    const int* dstp = ei + NE;

    char* w = (char*)d_ws;
    _Float16* h16 = (_Float16*)w;  w += sizeof(_Float16) * (size_t)NN * HD;
    float* featB = (float*)w;   w += sizeof(float) * (size_t)NN * HD;
    float* asv   = (float*)w;   w += sizeof(float) * NN;
    float* advv  = (float*)w;   w += sizeof(float) * NN;
    int* offs    = (int*)w;     w += sizeof(int) * (NN + 1);
    int* csr     = (int*)w;     w += sizeof(int) * (size_t)NE;
    int2* ebuf   = (int2*)w;    w += sizeof(int2) * (size_t)NE;
    int* gcnt    = (int*)w;     w += sizeof(int) * NBK;
    int* gbase   = (int*)w;     w += sizeof(int) * NBK;
    int* gcur    = (int*)w;     w += sizeof(int) * NBK;

    const int GBM = (NN + 63) / 64;   // BM=64 -> 1563 blocks

    // CSR build (bucketed counting sort; shared across all 3 layers)
    hipMemsetAsync(gcnt, 0, sizeof(int) * NBK, stream);
    bucket_hist<<<NBLK, 256, 0, stream>>>(dstp, gcnt);
    bucket_scan<<<1, 512, 0, stream>>>(gcnt, gbase, gcur);
    bin_edges<<<NBLK, 256, 0, stream>>>(srcp, dstp, gcur, ebuf);
    bucket_csr<<<NBK, 256, 0, stream>>>(ebuf, gbase, gcnt, offs, csr);

    // layer 1
    mfma_gemm<NF, HD><<<GBM, 128, 0, stream>>>(x, W1, as1, ad1, h16, asv, advv);
    gat_agg<HD, true><<<NN / 4, 256, 0, stream>>>(h16, asv, advv, offs, csr, b1, featB);

    // layer 2
    mfma_gemm<HD, HD><<<GBM, 128, 0, stream>>>(featB, W2, as2, ad2, h16, asv, advv);
    gat_agg<HD, true><<<NN / 4, 256, 0, stream>>>(h16, asv, advv, offs, csr, b2, featB);

    // layer 3
    mfma_gemm<HD, NC><<<GBM, 128, 0, stream>>>(featB, W3, as3, ad3, h16, asv, advv);
    gat_agg<NC, false><<<NN / 4, 256, 0, stream>>>(h16, asv, advv, offs, csr, b3, out);
}

// Round 9
// 423.859 us; speedup vs baseline: 1.1883x; 1.0088x over previous
//
#include <hip/hip_runtime.h>

#define NN 100000
#define NE 1600000
#define NF 256
#define HD 64
#define NC 32

#define BKS 8
#define NBK ((NN + 255) >> 8)      // 391 buckets of 256 nodes
#define CHUNK 4096                 // edges per bin_edges block
#define NBLK ((NE + CHUNK - 1) / CHUNK)  // 391

__device__ __forceinline__ float lrelu02(float x) { return fmaxf(x, 0.2f * x); }

typedef __attribute__((ext_vector_type(8))) short bf16x8;
typedef __attribute__((ext_vector_type(4))) float f32x4;
typedef __attribute__((ext_vector_type(8))) _Float16 f16x8;

// round-to-nearest-even f32 -> bf16 (finite inputs)
__device__ __forceinline__ unsigned short f2bf(float f) {
    unsigned int u = __float_as_uint(f);
    unsigned int r = u + 0x7FFFu + ((u >> 16) & 1u);
    return (unsigned short)(r >> 16);
}
__device__ __forceinline__ float bf2f(unsigned short s) {
    return __uint_as_float(((unsigned int)s) << 16);
}

// ---------------- CSR build via bucketed counting sort (packed edges: (src<<8)|dstlocal) ----------------

__global__ __launch_bounds__(256) void bucket_hist(const int* __restrict__ dst, int* __restrict__ gcnt) {
    __shared__ int hist[NBK];
    int tid = threadIdx.x;
    for (int i = tid; i < NBK; i += 256) hist[i] = 0;
    __syncthreads();
    int base = blockIdx.x * CHUNK;
    #pragma unroll
    for (int k = 0; k < CHUNK / 256; k++) {
        int i = base + k * 256 + tid;
        if (i < NE) atomicAdd(&hist[dst[i] >> BKS], 1);
    }
    __syncthreads();
    for (int i = tid; i < NBK; i += 256) if (hist[i]) atomicAdd(&gcnt[i], hist[i]);
}

__global__ void bucket_scan(const int* __restrict__ gcnt, int* __restrict__ gbase, int* __restrict__ gcur) {
    __shared__ int sh[512];
    int tid = threadIdx.x;
    int v = (tid < NBK) ? gcnt[tid] : 0;
    sh[tid] = v;
    __syncthreads();
    for (int d = 1; d < 512; d <<= 1) {
        int t = (tid >= d) ? sh[tid - d] : 0;
        __syncthreads();
        sh[tid] += t;
        __syncthreads();
    }
    if (tid < NBK) { int ex = sh[tid] - v; gbase[tid] = ex; gcur[tid] = ex; }
}

__global__ __launch_bounds__(256) void bin_edges(const int* __restrict__ src, const int* __restrict__ dst,
                                                 int* __restrict__ gcur, unsigned int* __restrict__ ebuf) {
    __shared__ int hist[NBK];
    __shared__ int excl[NBK];
    __shared__ int runbase[NBK];
    __shared__ int ssum[256];
    __shared__ unsigned int sorted[CHUNK];     // 16 KB (packed edges)
    __shared__ unsigned short sortedb[CHUNK];  // 8 KB (bucket ids, 391 > 255 needs 16b)
    int tid = threadIdx.x;
    int base = blockIdx.x * CHUNK;
    int n = NE - base; if (n > CHUNK) n = CHUNK;

    for (int i = tid; i < NBK; i += 256) hist[i] = 0;
    __syncthreads();

    unsigned int pk[CHUNK / 256];
    int bk[CHUNK / 256];
    #pragma unroll
    for (int k = 0; k < CHUNK / 256; k++) {
        int i = base + k * 256 + tid;
        if (i < NE) {
            int s = src[i], d = dst[i];
            pk[k] = ((unsigned int)s << 8) | ((unsigned int)d & 255u);
            bk[k] = d >> BKS;
            atomicAdd(&hist[bk[k]], 1);
        } else bk[k] = -1;
    }
    __syncthreads();
    int h0 = (2 * tid < NBK) ? hist[2 * tid] : 0;
    int h1 = (2 * tid + 1 < NBK) ? hist[2 * tid + 1] : 0;
    ssum[tid] = h0 + h1;
    __syncthreads();
    for (int d = 1; d < 256; d <<= 1) {
        int t = (tid >= d) ? ssum[tid - d] : 0;
        __syncthreads();
        ssum[tid] += t;
        __syncthreads();
    }
    int pref = ssum[tid] - (h0 + h1);
    if (2 * tid < NBK) excl[2 * tid] = pref;
    if (2 * tid + 1 < NBK) excl[2 * tid + 1] = pref + h0;
    for (int b = tid; b < NBK; b += 256) {
        int c = hist[b];
        runbase[b] = c ? atomicAdd(&gcur[b], c) : 0;
    }
    __syncthreads();
    #pragma unroll
    for (int k = 0; k < CHUNK / 256; k++) {
        if (bk[k] >= 0) {
            int r = atomicAdd(&excl[bk[k]], 1);
            sorted[r] = pk[k];
            sortedb[r] = (unsigned short)bk[k];
        }
    }
    __syncthreads();
    for (int i = tid; i < n; i += 256) {
        int b = sortedb[i];
        int local_rank = i - (excl[b] - hist[b]);
        ebuf[runbase[b] + local_rank] = sorted[i];
    }
}

__global__ __launch_bounds__(256) void bucket_csr(const unsigned int* __restrict__ ebuf, const int* __restrict__ gbase,
                                                  const int* __restrict__ gcnt,
                                                  int* __restrict__ offs, int* __restrict__ csr) {
    __shared__ int hist[256], cur[256], ssum[256];
    int b = blockIdx.x, tid = threadIdx.x;
    int ebeg = gbase[b], cnt = gcnt[b];
    int node0 = b << BKS;
    hist[tid] = 0;
    __syncthreads();
    for (int i = ebeg + tid; i < ebeg + cnt; i += 256)
        atomicAdd(&hist[ebuf[i] & 255u], 1);
    __syncthreads();
    int v = hist[tid];
    ssum[tid] = v;
    __syncthreads();
    for (int d = 1; d < 256; d <<= 1) {
        int t = (tid >= d) ? ssum[tid - d] : 0;
        __syncthreads();
        ssum[tid] += t;
        __syncthreads();
    }
    int ex = ebeg + ssum[tid] - v;
    cur[tid] = ex;
    int nnode = NN - node0; if (nnode > 256) nnode = 256;
    if (tid < nnode) offs[node0 + tid] = ex;
    if (b == NBK - 1 && tid == nnode - 1) offs[NN] = ebeg + cnt;
    __syncthreads();
    for (int i = ebeg + tid; i < ebeg + cnt; i += 256) {
        unsigned int e = ebuf[i];
        int pos = atomicAdd(&cur[e & 255u], 1);
        csr[pos] = (int)(e >> 8);
    }
}

// ---------------- split-bf16 MFMA GEMM: A in registers, B in LDS, 2-wave blocks (unchanged R8) ----------------

template <int CIN, int COUT>
__global__ __launch_bounds__(128) void mfma_gemm(const float* __restrict__ in, const float* __restrict__ W,
                                                 const float* __restrict__ a_s, const float* __restrict__ a_d,
                                                 _Float16* __restrict__ hout, float* __restrict__ asv,
                                                 float* __restrict__ adv) {
    const int KC  = 32;
    const int BM  = 64;
    const int NCT = COUT / 16;       // col tiles: 4 (COUT=64) or 2 (COUT=32)
    const int NCH = CIN / KC;
    const int SPT = (4 * COUT) / 128;  // (kg,col) slots per thread: 2 or 1

    __shared__ unsigned short Bh[2][4 * COUT * 8];   // 8 / 4 KB
    __shared__ unsigned short Bl[2][4 * COUT * 8];

    int tid  = threadIdx.x;
    int lane = tid & 63;
    int wave = tid >> 6;             // 0..1
    int fr = lane & 15;              // free-dim index within 16-tile
    int kg = lane >> 4;              // k-group (0..3), 8 k each
    int n0base = blockIdx.x * BM;
    int rbase  = n0base + wave * 32;

    int scol[SPT], skg[SPT];
    #pragma unroll
    for (int i = 0; i < SPT; i++) {
        int s = tid + i * 128;
        scol[i] = s % COUT;
        skg[i]  = s / COUT;
    }

    float4 xr[4];
    float  wv[SPT][8];
    bf16x8 ah[2], al[2];

    f32x4 acc[2][NCT];
    #pragma unroll
    for (int rt = 0; rt < 2; rt++)
        #pragma unroll
        for (int ct = 0; ct < NCT; ct++) acc[rt][ct] = (f32x4){0.f, 0.f, 0.f, 0.f};

    auto load_A = [&](int k0) {
        #pragma unroll
        for (int rt = 0; rt < 2; rt++) {
            int gr = rbase + rt * 16 + fr;
            if (gr < NN) {
                const float* p = &in[(size_t)gr * CIN + k0 + kg * 8];
                xr[rt * 2 + 0] = *(const float4*)p;
                xr[rt * 2 + 1] = *(const float4*)(p + 4);
            } else {
                xr[rt * 2 + 0] = make_float4(0.f, 0.f, 0.f, 0.f);
                xr[rt * 2 + 1] = make_float4(0.f, 0.f, 0.f, 0.f);
            }
        }
    };
    auto conv_A = [&]() {
        #pragma unroll
        for (int rt = 0; rt < 2; rt++) {
            const float* v = (const float*)&xr[rt * 2];
            unsigned short hs[8], ls[8];
            #pragma unroll
            for (int j = 0; j < 8; j++) {
                hs[j] = f2bf(v[j]);
                ls[j] = f2bf(v[j] - bf2f(hs[j]));
            }
            ah[rt] = *(bf16x8*)hs;
            al[rt] = *(bf16x8*)ls;
        }
    };
    auto load_B = [&](int k0) {
        #pragma unroll
        for (int i = 0; i < SPT; i++)
            #pragma unroll
            for (int j = 0; j < 8; j++)
                wv[i][j] = W[(size_t)(k0 + skg[i] * 8 + j) * COUT + scol[i]];
    };
    auto write_B = [&](int buf) {
        #pragma unroll
        for (int i = 0; i < SPT; i++) {
            unsigned short hs[8], ls[8];
            #pragma unroll
            for (int j = 0; j < 8; j++) {
                hs[j] = f2bf(wv[i][j]);
                ls[j] = f2bf(wv[i][j] - bf2f(hs[j]));
            }
            int idx = (skg[i] * COUT + scol[i]) * 8;
            *(uint4*)&Bh[buf][idx] = *(uint4*)hs;
            *(uint4*)&Bl[buf][idx] = *(uint4*)ls;
        }
    };
    auto do_mfma = [&](int buf) {
        #pragma unroll
        for (int ct = 0; ct < NCT; ct++) {
            int col = ct * 16 + fr;
            bf16x8 bh = *(const bf16x8*)&Bh[buf][(kg * COUT + col) * 8];
            bf16x8 bl = *(const bf16x8*)&Bl[buf][(kg * COUT + col) * 8];
            #pragma unroll
            for (int rt = 0; rt < 2; rt++) {
                acc[rt][ct] = __builtin_amdgcn_mfma_f32_16x16x32_bf16(ah[rt], bh, acc[rt][ct], 0, 0, 0);
                acc[rt][ct] = __builtin_amdgcn_mfma_f32_16x16x32_bf16(ah[rt], bl, acc[rt][ct], 0, 0, 0);
                acc[rt][ct] = __builtin_amdgcn_mfma_f32_16x16x32_bf16(al[rt], bh, acc[rt][ct], 0, 0, 0);
            }
        }
    };

    load_A(0);
    load_B(0);
    conv_A();
    write_B(0);
    __syncthreads();

    for (int t = 0; t < NCH; t++) {
        int cur = t & 1;
        if (t + 1 < NCH) {
            load_A((t + 1) * KC);
            load_B((t + 1) * KC);
        }
        do_mfma(cur);
        if (t + 1 < NCH) {
            write_B(cur ^ 1);
            conv_A();
            __syncthreads();
        }
    }

    float As_l[NCT], Ad_l[NCT];
    #pragma unroll
    for (int ct = 0; ct < NCT; ct++) {
        As_l[ct] = a_s[ct * 16 + fr];
        Ad_l[ct] = a_d[ct * 16 + fr];
    }
    #pragma unroll
    for (int rt = 0; rt < 2; rt++) {
        #pragma unroll
        for (int r = 0; r < 4; r++) {
            int row = rbase + rt * 16 + kg * 4 + r;
            if (row < NN) {
                #pragma unroll
                for (int ct = 0; ct < NCT; ct++)
                    hout[(size_t)row * COUT + ct * 16 + fr] = (_Float16)acc[rt][ct][r];
            }
            float ps = 0.f, pd = 0.f;
            #pragma unroll
            for (int ct = 0; ct < NCT; ct++) {
                ps += acc[rt][ct][r] * As_l[ct];
                pd += acc[rt][ct][r] * Ad_l[ct];
            }
            #pragma unroll
            for (int off = 1; off < 16; off <<= 1) {
                ps += __shfl_xor(ps, off);
                pd += __shfl_xor(pd, off);
            }
            if (fr == 0 && row < NN) { asv[row] = ps; adv[row] = pd; }
        }
    }
}

// ---------------- fused aggregate: 16B/lane gather, 2x edges in flight ----------------
// LR = C/8 lanes per row (each lane loads one f16x8 = 16 B, the coalescing sweet spot);
// G = 64/LR edges in flight per wave (8 for C=64, 16 for C=32) -> 2x the independent
// gathers per wave vs the 8B/lane layout, half the load instructions per edge.

template <int C, bool ACT>
__global__ __launch_bounds__(256) void gat_agg(const _Float16* __restrict__ h16, const float* __restrict__ asv,
                                               const float* __restrict__ adv, const int* __restrict__ offs,
                                               const int* __restrict__ csr,
                                               const float* __restrict__ bias, float* __restrict__ out) {
    const int LR = C / 8;            // lanes per row: 8 (C=64) or 4 (C=32)
    const int G  = 64 / LR;          // edges in flight: 8 or 16
    const f16x8* hh = (const f16x8*)h16;
    int lane = threadIdx.x & 63;
    int v = blockIdx.x * 4 + (threadIdx.x >> 6);
    int beg = offs[v], end = offs[v + 1];
    int g = lane / LR, r = lane % LR;
    float adv_v = adv[v];

    float acc[8] = {0.f, 0.f, 0.f, 0.f, 0.f, 0.f, 0.f, 0.f};
    float dsum = 0.f;
    #pragma unroll 4
    for (int e = beg + g; e < end; e += G) {
        int s = csr[e];
        float ww = __expf(lrelu02(asv[s] + adv_v));
        f16x8 hv = hh[(size_t)s * LR + r];
        dsum += ww;
        #pragma unroll
        for (int j = 0; j < 8; j++) acc[j] += ww * (float)hv[j];
    }
    #pragma unroll
    for (int off = LR; off < 64; off <<= 1) {
        #pragma unroll
        for (int j = 0; j < 8; j++) acc[j] += __shfl_xor(acc[j], off);
        dsum += __shfl_xor(dsum, off);
    }
    if (g == 0) {
        float selfw = __expf(lrelu02(asv[v] + adv_v));
        f16x8 hs = hh[(size_t)v * LR + r];
        #pragma unroll
        for (int j = 0; j < 8; j++) acc[j] += selfw * (float)hs[j];
        dsum += selfw;
        float inv = 1.f / (dsum + 1e-16f);
        float4 bb0 = ((const float4*)bias)[r * 2];
        float4 bb1 = ((const float4*)bias)[r * 2 + 1];
        float4 o0, o1;
        o0.x = acc[0] * inv + bb0.x; o0.y = acc[1] * inv + bb0.y;
        o0.z = acc[2] * inv + bb0.z; o0.w = acc[3] * inv + bb0.w;
        o1.x = acc[4] * inv + bb1.x; o1.y = acc[5] * inv + bb1.y;
        o1.z = acc[6] * inv + bb1.z; o1.w = acc[7] * inv + bb1.w;
        if (ACT) {
            o0.x = fmaxf(o0.x, 0.01f * o0.x); o0.y = fmaxf(o0.y, 0.01f * o0.y);
            o0.z = fmaxf(o0.z, 0.01f * o0.z); o0.w = fmaxf(o0.w, 0.01f * o0.w);
            o1.x = fmaxf(o1.x, 0.01f * o1.x); o1.y = fmaxf(o1.y, 0.01f * o1.y);
            o1.z = fmaxf(o1.z, 0.01f * o1.z); o1.w = fmaxf(o1.w, 0.01f * o1.w);
        }
        ((float4*)out)[(size_t)v * (C / 4) + r * 2]     = o0;
        ((float4*)out)[(size_t)v * (C / 4) + r * 2 + 1] = o1;
    }
}

// ---------------- launch ----------------

extern "C" void kernel_launch(void* const* d_in, const int* in_sizes, int n_in,
                              void* d_out, int out_size, void* d_ws, size_t ws_size,
                              hipStream_t stream) {
    const float* x   = (const float*)d_in[0];
    const int*   ei  = (const int*)d_in[1];
    const float* W1  = (const float*)d_in[2];
    const float* as1 = (const float*)d_in[3];
    const float* ad1 = (const float*)d_in[4];
    const float* b1  = (const float*)d_in[5];
    const float* W2  = (const float*)d_in[6];
    const float* as2 = (const float*)d_in[7];
    const float* ad2 = (const float*)d_in[8];
    const float* b2  = (const float*)d_in[9];
    const float* W3  = (const float*)d_in[10];
    const float* as3 = (const float*)d_in[11];
    const float* ad3 = (const float*)d_in[12];
    const float* b3  = (const float*)d_in[13];
    float* out = (float*)d_out;

    const int* srcp = ei;
    const int* dstp = ei + NE;

    char* w = (char*)d_ws;
    _Float16* h16 = (_Float16*)w;  w += sizeof(_Float16) * (size_t)NN * HD;
    float* featB = (float*)w;   w += sizeof(float) * (size_t)NN * HD;
    float* asv   = (float*)w;   w += sizeof(float) * NN;
    float* advv  = (float*)w;   w += sizeof(float) * NN;
    int* offs    = (int*)w;     w += sizeof(int) * (NN + 1);
    int* csr     = (int*)w;     w += sizeof(int) * (size_t)NE;
    unsigned int* ebuf = (unsigned int*)w; w += sizeof(unsigned int) * (size_t)NE;
    int* gcnt    = (int*)w;     w += sizeof(int) * NBK;
    int* gbase   = (int*)w;     w += sizeof(int) * NBK;
    int* gcur    = (int*)w;     w += sizeof(int) * NBK;

    const int GBM = (NN + 63) / 64;   // BM=64 -> 1563 blocks

    // CSR build (bucketed counting sort; shared across all 3 layers)
    hipMemsetAsync(gcnt, 0, sizeof(int) * NBK, stream);
    bucket_hist<<<NBLK, 256, 0, stream>>>(dstp, gcnt);
    bucket_scan<<<1, 512, 0, stream>>>(gcnt, gbase, gcur);
    bin_edges<<<NBLK, 256, 0, stream>>>(srcp, dstp, gcur, ebuf);
    bucket_csr<<<NBK, 256, 0, stream>>>(ebuf, gbase, gcnt, offs, csr);

    // layer 1
    mfma_gemm<NF, HD><<<GBM, 128, 0, stream>>>(x, W1, as1, ad1, h16, asv, advv);
    gat_agg<HD, true><<<NN / 4, 256, 0, stream>>>(h16, asv, advv, offs, csr, b1, featB);

    // layer 2
    mfma_gemm<HD, HD><<<GBM, 128, 0, stream>>>(featB, W2, as2, ad2, h16, asv, advv);
    gat_agg<HD, true><<<NN / 4, 256, 0, stream>>>(h16, asv, advv, offs, csr, b2, featB);

    // layer 3
    mfma_gemm<HD, NC><<<GBM, 128, 0, stream>>>(featB, W3, as3, ad3, h16, asv, advv);
    gat_agg<NC, false><<<NN / 4, 256, 0, stream>>>(h16, asv, advv, offs, csr, b3, out);
}